// Round 10
// baseline (1251.129 us; speedup 1.0000x reference)
//
#include <hip/hip_runtime.h>
#include <math.h>

// RPN forward: fused conv3x3+relu -> fused 1x1 heads ->
// [topk + decode + per-group sort + NMS + compact] (one 10-block kernel) ->
// per-image 5-way merge select. 5 dispatches total.
// Precision: f64 accumulation + f64 logits/regs/h -> all selection decisions
// match the float64 numpy reference exactly (absmax 0 through R2-R9).
// Conv ladder: R3 reg-dbuf FAIL; R4 cvt tax; R5 occ/L2 FAIL; R6/R9 851us
// (VALU 66%: ~400us FMA floor + 160us staging VALU + 290us idle);
// R7 scalar-weight stall FAIL; R8 stride-13 FAIL.
// R9 lesson: SQ_LDS_BANK_CONFLICT identical (7.354e7) across R6/R7/R9 ->
// counter dominated by b64 staging writes / intrinsic phases, NOT read
// stride. Lever is ISSUE DENSITY, not conflicts.
// R10: 8px/thread (tile 8x16, 64co): FMA/chunk/wave 2x (576->1152 cyc),
// LDS instrs only 108->132 (weight reads amortized 2x), barriers per FMA
// halved. s_in stride 18 (2-way max, 16B aligned). 1040 blocks = 8x130.

#define N_IMG 2
#define C_CH  256
#define D_PER 2147
#define K_TOT 4294
#define CONV_BLOCKS 1040
#define CPX 130              // CONV_BLOCKS / 8 XCDs (exact)

__constant__ int c_Ml[5]     = {30000, 7500, 1875, 507, 147};
__constant__ int c_kl[5]     = {500, 500, 500, 500, 147};
__constant__ int c_logoff[5] = {0, 60000, 75000, 78750, 79764};   // 6*cumE
__constant__ int c_regoff[5] = {0, 240000, 300000, 315000, 319056}; // 24*cumE
__constant__ int c_fs[5]     = {100, 50, 25, 13, 7};
__constant__ int c_npty[5]   = {13, 7, 4, 2, 1};
__constant__ int c_nptx[5]   = {7, 4, 2, 1, 1};
__constant__ int c_E[5]      = {10000, 2500, 625, 169, 49};
__constant__ int c_cumbl[6]  = {0, 728, 952, 1016, 1032, 1040};
__constant__ int c_hcum[6]   = {0, 157, 197, 207, 210, 211};
__constant__ size_t c_hoff[5] = {0, 5120000, 6400000, 6720000, 6806528};

// ------- weight repack+convert: slabs of 2304 f64 = [ci4][tap9][co64] ----
__global__ void transpose_w_kernel(const float* __restrict__ w,
                                   double* __restrict__ wT2) {
  int i = blockIdx.x * 256 + threadIdx.x;
  if (i >= 589824) return;
  int q = i % 2304;
  int slab = i / 2304;
  int cobi = slab >> 6, ch = slab & 63;
  int ci = q / 576;
  int rem = q % 576;
  int tap = rem / 64, co = rem & 63;
  wT2[i] =
      (double)w[(size_t)(cobi * 64 + co) * 2304 + (ch * 4 + ci) * 9 + tap];
}

// ------- fused conv3x3 (SAME) + bias + relu, all 5 levels, f64 acc -------
// block: 256 thr = 16 px-slots x 16 co-slots; tile 64co x (8 rows x 16 cols);
// thread: 4co x 8px (one half-row). CI_CHUNK=4, 64 chunks.
// s_in: [ci][10 rows x 18 cols], stride 18 doubles: slot addresses
// prow*36 + c0*2 mod 32 -> 2-way max; 16B aligned (b128 kept).
template <typename T>
__global__ __launch_bounds__(256) void conv_fused_kernel(
    const float* __restrict__ x0, const float* __restrict__ x1,
    const float* __restrict__ x2, const float* __restrict__ x3,
    const float* __restrict__ x4, const double* __restrict__ wT2,
    const float* __restrict__ bias, T* __restrict__ h) {
  __shared__ double s_in[4 * 180];   // [ci][10*18]
  __shared__ double s_w[2304];       // [ci4][tap][co64]
  int tid = threadIdx.x;
  int bid = (blockIdx.x & 7) * CPX + (blockIdx.x >> 3);  // XCD swizzle
  int l = 0;
  while (bid >= c_cumbl[l + 1]) ++l;
  int r = bid - c_cumbl[l];
  int fs = c_fs[l];
  int nptx = c_nptx[l], npty = c_npty[l];
  int tiles = nptx * npty;
  int tile = r % tiles;
  int cn = r / tiles;
  int cobi = cn & 3, n = cn >> 2;
  int ptx = tile % nptx, pty = tile / nptx;
  int px0 = ptx * 16, py0 = pty * 8;
  int E = fs * fs;
  const float* xl;
  switch (l) {
    case 0: xl = x0; break;
    case 1: xl = x1; break;
    case 2: xl = x2; break;
    case 3: xl = x3; break;
    default: xl = x4; break;
  }
  const float* xn = xl + (size_t)n * C_CH * E;
  T* hl = h + c_hoff[l];

  int tpx = tid & 15, tco = tid >> 4;
  int prow = tpx >> 1, c0 = (tpx & 1) * 8;

  // staging descriptors: 720 halo elems over 256 threads (3 slots)
  int in_dst[3], in_src[3];
#pragma unroll
  for (int it = 0; it < 3; ++it) {
    int idx = tid + it * 256;
    in_dst[it] = -1;
    in_src[it] = -1;
    if (idx < 720) {
      int ci = idx / 180, rr2 = idx % 180;
      int hy = rr2 / 18, hx = rr2 % 18;
      int gy = py0 - 1 + hy, gx = px0 - 1 + hx;
      in_dst[it] = ci * 180 + hy * 18 + hx;
      if (gy >= 0 && gy < fs && gx >= 0 && gx < fs)
        in_src[it] = ci * E + gy * fs + gx;
    }
  }

  double acc[4][8];
#pragma unroll
  for (int i = 0; i < 4; i++)
#pragma unroll
    for (int j = 0; j < 8; j++) acc[i][j] = 0.0;

  const double2* wsrc0 = (const double2*)(wT2 + (size_t)cobi * 64 * 2304);

  for (int ch = 0; ch < 64; ++ch) {
    const float* xc = xn + (size_t)ch * 4 * E;
#pragma unroll
    for (int it = 0; it < 3; ++it) {
      if (in_dst[it] >= 0)
        s_in[in_dst[it]] = (in_src[it] >= 0) ? (double)xc[in_src[it]] : 0.0;
    }
    {
      const double2* src = wsrc0 + (size_t)ch * 1152;
      double2* dst = (double2*)s_w;
#pragma unroll
      for (int k = 0; k < 5; k++) {
        int idx = tid + k * 256;
        if (idx < 1152) dst[idx] = src[idx];
      }
    }
    __syncthreads();
#pragma unroll
    for (int ci = 0; ci < 4; ++ci) {
      const double* inp = &s_in[ci * 180];
      const double* wpb = &s_w[ci * 576];
#pragma unroll
      for (int ky = 0; ky < 3; ++ky) {
        const double* ip = inp + (prow + ky) * 18 + c0;
        double2 b0 = *(const double2*)(ip + 0);
        double2 b1 = *(const double2*)(ip + 2);
        double2 b2 = *(const double2*)(ip + 4);
        double2 b3 = *(const double2*)(ip + 6);
        double2 b4 = *(const double2*)(ip + 8);
        double d[10];
        d[0] = b0.x; d[1] = b0.y; d[2] = b1.x; d[3] = b1.y;
        d[4] = b2.x; d[5] = b2.y; d[6] = b3.x; d[7] = b3.y;
        d[8] = b4.x; d[9] = b4.y;
#pragma unroll
        for (int kx = 0; kx < 3; ++kx) {
          const double* wp = wpb + (ky * 3 + kx) * 64 + tco * 4;
          double2 wA = *(const double2*)wp;
          double2 wB = *(const double2*)(wp + 2);
          double w0 = wA.x, w1 = wA.y, w2 = wB.x, w3 = wB.y;
#pragma unroll
          for (int pj = 0; pj < 8; pj++) {
            double iv = d[kx + pj];
            acc[0][pj] = fma(w0, iv, acc[0][pj]);
            acc[1][pj] = fma(w1, iv, acc[1][pj]);
            acc[2][pj] = fma(w2, iv, acc[2][pj]);
            acc[3][pj] = fma(w3, iv, acc[3][pj]);
          }
        }
      }
    }
    __syncthreads();
  }

  int gy = py0 + prow;
  if (gy < fs) {
#pragma unroll
    for (int coi = 0; coi < 4; ++coi) {
      int co = cobi * 64 + tco * 4 + coi;
      double bb = (double)bias[co];
#pragma unroll
      for (int pj = 0; pj < 8; pj++) {
        int gx = px0 + c0 + pj;
        if (gx < fs) {
          double v = acc[coi][pj] + bb;
          hl[((size_t)n * C_CH + co) * E + gy * fs + gx] = (T)fmax(v, 0.0);
        }
      }
    }
  }
}

// ------- fused 1x1 heads: 64 px x 4 c-groups per block, LDS reduce -------
template <typename T>
__global__ __launch_bounds__(256) void heads_fused_kernel(
    const T* __restrict__ h, const float* __restrict__ logw,
    const float* __restrict__ logb, const float* __restrict__ regw,
    const float* __restrict__ regb, double* __restrict__ logits,
    double* __restrict__ regs) {
  __shared__ float s_wh[256][16];
  __shared__ double s_red[4][15][64];
  int tid = threadIdx.x;
  int n = blockIdx.y;
  int cidx = blockIdx.x;
  int l = 0;
  while (cidx >= c_hcum[l + 1]) ++l;
  int chunk = cidx - c_hcum[l];
  int E = c_E[l];
  int px0 = chunk * 64;
  const T* hl = h + c_hoff[l];
  double* logits_l = logits + c_logoff[l];
  double* regs_l = regs + c_regoff[l];

  for (int idx = tid; idx < 4096; idx += 256) {
    int c = idx >> 4, j = idx & 15;
    float v = 0.f;
    if (j < 3) v = logw[j * 256 + c];
    else if (j < 15) v = regw[(j - 3) * 256 + c];
    s_wh[c][j] = v;
  }
  __syncthreads();

  int p = tid & 63, c4 = tid >> 6;
  int pix = px0 + p;
  bool act = pix < E;
  double acc[15];
#pragma unroll
  for (int j = 0; j < 15; j++) acc[j] = 0.0;
  if (act) {
    const T* hp = hl + ((size_t)n * C_CH + c4 * 64) * E + pix;
    for (int cc = 0; cc < 64; ++cc) {
      double hv = (double)hp[(size_t)cc * E];
      const float* wr = &s_wh[c4 * 64 + cc][0];
#pragma unroll
      for (int j = 0; j < 15; j++)
        acc[j] = fma((double)wr[j], hv, acc[j]);
    }
  }
#pragma unroll
  for (int j = 0; j < 15; j++) s_red[c4][j][p] = acc[j];
  __syncthreads();
  if (act) {
    int M = E * 3;
    for (int j = c4; j < 15; j += 4) {
      double v = s_red[0][j][p] + s_red[1][j][p] + s_red[2][j][p] +
                 s_red[3][j][p];
      if (j < 3) {
        logits_l[(size_t)n * M + pix * 3 + j] = v + (double)logb[j];
      } else {
        int rj = j - 3, a = rj >> 2, coord = rj & 3;
        regs_l[((size_t)n * M + pix * 3 + a) * 4 + coord] =
            v + (double)regb[rj];
      }
    }
  }
}

// ------- topk + decode + per-group sort + NMS + compact (10 blocks) ------
__device__ __forceinline__ unsigned long long d2key(double v) {
  unsigned long long ub = (unsigned long long)__double_as_longlong(v);
  return (ub >> 63) ? ~ub : (ub | 0x8000000000000000ull);
}

#define TK_CH 30
union TkShared {
  struct {
    int histw[16][256];
    int hist[256];
    int sgt[1024];
    int seq[1024];
  } a;
  struct {
    unsigned long long u[512];
    int idx[512];
    int keep[512];
    int ps[512];
    int m;
    double bx[512][4];
    unsigned long long mask[512][8];
  } b;
};

__global__ __launch_bounds__(1024) void topk_nms_kernel(
    const double* __restrict__ logits, const double* __restrict__ regs,
    const float* __restrict__ p0, const float* __restrict__ p1,
    const float* __restrict__ p2, const float* __restrict__ p3,
    const float* __restrict__ p4, const int* __restrict__ imsizes,
    double* __restrict__ g_box, unsigned long long* __restrict__ g_u,
    int* __restrict__ g_cnt) {
  __shared__ TkShared sh;
  __shared__ int s_sel[512];
  __shared__ unsigned long long s_prefix;
  __shared__ int s_r;
  int bid = blockIdx.x;
  int n = bid / 5, l = bid % 5;
  int M = c_Ml[l], k = c_kl[l];
  const double* lg = logits + c_logoff[l] + (size_t)n * M;
  int tid = threadIdx.x;
  if (tid == 0) { s_prefix = 0ull; s_r = k; }

  int chunk = (M + 1023) >> 10;
  int i0 = tid * chunk, i1 = min(M, i0 + chunk);
  int cnt = i1 - i0;
  if (cnt < 0) cnt = 0;
  unsigned long long kv[TK_CH];
#pragma unroll
  for (int q = 0; q < TK_CH; q++)
    if (q < cnt) kv[q] = d2key(lg[i0 + q]);
  int wid = tid >> 6;
  __syncthreads();

  for (int pass = 0; pass < 8; ++pass) {
    int shift = 56 - pass * 8;
    for (int i = tid; i < 4096; i += 1024) ((int*)sh.a.histw)[i] = 0;
    __syncthreads();
    unsigned long long pfx = s_prefix;
    int rr = s_r;
#pragma unroll
    for (int q = 0; q < TK_CH; q++) {
      if (q < cnt) {
        unsigned long long u = kv[q];
        if (pass == 0 || (u >> (shift + 8)) == pfx)
          atomicAdd(&sh.a.histw[wid][(int)((u >> shift) & 255ull)], 1);
      }
    }
    __syncthreads();
    if (tid < 256) {
      int s = 0;
#pragma unroll
      for (int w = 0; w < 16; w++) s += sh.a.histw[w][tid];
      sh.a.hist[tid] = s;
    }
    __syncthreads();
    if (tid == 0) {
      int s = 0, beta = 0;
      for (int b = 255; b >= 0; --b) {
        if (s + sh.a.hist[b] >= rr) { beta = b; break; }
        s += sh.a.hist[b];
      }
      s_prefix = (pfx << 8) | (unsigned long long)beta;
      s_r = rr - s;
    }
    __syncthreads();
  }
  unsigned long long T = s_prefix;
  int need = s_r;
  int cgt = 0, ceq = 0;
#pragma unroll
  for (int q = 0; q < TK_CH; q++) {
    if (q < cnt) {
      cgt += (kv[q] > T);
      ceq += (kv[q] == T);
    }
  }
  sh.a.sgt[tid] = cgt;
  sh.a.seq[tid] = ceq;
  __syncthreads();
  for (int o = 1; o < 1024; o <<= 1) {
    int a = (tid >= o) ? sh.a.sgt[tid - o] : 0;
    int b2 = (tid >= o) ? sh.a.seq[tid - o] : 0;
    __syncthreads();
    sh.a.sgt[tid] += a;
    sh.a.seq[tid] += b2;
    __syncthreads();
  }
  int gt_total = sh.a.sgt[1023];
  int pg = sh.a.sgt[tid] - cgt, pe = sh.a.seq[tid] - ceq;
#pragma unroll
  for (int q = 0; q < TK_CH; q++) {
    if (q < cnt) {
      unsigned long long u = kv[q];
      if (u > T) {
        s_sel[pg++] = i0 + q;
      } else if (u == T) {
        if (pe < need) s_sel[gt_total + pe] = i0 + q;
        pe++;
      }
    }
  }
  __syncthreads();

  const float* pp;
  switch (l) {
    case 0: pp = p0; break;
    case 1: pp = p1; break;
    case 2: pp = p2; break;
    case 3: pp = p3; break;
    default: pp = p4; break;
  }
  const double* regs_l = regs + c_regoff[l];
  double imh = (double)imsizes[n * 2 + 0], imw = (double)imsizes[n * 2 + 1];
  const double BCLIP = 4.1351665567423560;
  if (tid < 512) {
    unsigned long long key = 0ull;
    sh.b.idx[tid] = tid;
    sh.b.keep[tid] = 0;
    if (tid < k) {
      int aidx = s_sel[tid];
      double lv = lg[aidx];
      double obj = 1.0 / (1.0 + exp(-lv));
      const double* rp = regs_l + ((size_t)n * M + aidx) * 4;
      const float* pr = pp + (size_t)aidx * 4;
      double px1 = pr[0], py1 = pr[1], px2 = pr[2], py2 = pr[3];
      double pw = px2 - px1, ph = py2 - py1;
      double pcx = px1 + 0.5 * pw, pcy = py1 + 0.5 * ph;
      double dx = rp[0], dy = rp[1];
      double dw = fmin(rp[2], BCLIP), dh = fmin(rp[3], BCLIP);
      double cx = dx * pw + pcx, cy = dy * ph + pcy;
      double w = exp(dw) * pw, hh = exp(dh) * ph;
      double x1 = cx - 0.5 * w, y1 = cy - 0.5 * hh;
      double x2 = cx + 0.5 * w, y2 = cy + 0.5 * hh;
      x1 = fmin(fmax(x1, 0.0), imw);
      x2 = fmin(fmax(x2, 0.0), imw);
      y1 = fmin(fmax(y1, 0.0), imh);
      y2 = fmin(fmax(y2, 0.0), imh);
      bool valid = (obj >= 0.5) && ((x2 - x1) >= 1.0) && ((y2 - y1) >= 1.0);
      sh.b.bx[tid][0] = x1;
      sh.b.bx[tid][1] = y1;
      sh.b.bx[tid][2] = x2;
      sh.b.bx[tid][3] = y2;
      if (valid) key = d2key(obj);
    }
    sh.b.u[tid] = key;
  }
  if (tid == 0) sh.b.m = 0;
  __syncthreads();

  for (int kk = 2; kk <= 512; kk <<= 1) {
    for (int j = kk >> 1; j > 0; j >>= 1) {
      if (tid < 512) {
        int i = tid, ixj = i ^ j;
        if (ixj > i) {
          unsigned long long ua = sh.b.u[i], ub = sh.b.u[ixj];
          int ia = sh.b.idx[i], ib = sh.b.idx[ixj];
          bool up = ((i & kk) == 0);
          bool aAfterB = (ua < ub) || (ua == ub && ia > ib);
          bool sw = up ? aAfterB : !aAfterB && (ua != ub || ia != ib);
          if (sw) {
            sh.b.u[i] = ub; sh.b.u[ixj] = ua;
            sh.b.idx[i] = ib; sh.b.idx[ixj] = ia;
          }
        }
      }
      __syncthreads();
    }
  }
  if (tid < 512) {
    if (sh.b.u[tid] != 0ull && (tid == 511 || sh.b.u[tid + 1] == 0ull))
      sh.b.m = tid + 1;
  }
  __syncthreads();
  int m = sh.b.m;

  if (tid < 512 && tid < m) {
    int i = tid;
    const double* A = sh.b.bx[sh.b.idx[i]];
    double ax1 = A[0], ay1 = A[1], ax2 = A[2], ay2 = A[3];
    double areaA = (ax2 - ax1) * (ay2 - ay1);
    unsigned long long row[8] = {0, 0, 0, 0, 0, 0, 0, 0};
    for (int j = i + 1; j < m; ++j) {
      const double* B = sh.b.bx[sh.b.idx[j]];
      double bx1 = B[0], by1 = B[1], bx2 = B[2], by2 = B[3];
      double areaB = (bx2 - bx1) * (by2 - by1);
      double lx = fmax(ax1, bx1), ly = fmax(ay1, by1);
      double rx = fmin(ax2, bx2), ry = fmin(ay2, by2);
      double iw = fmax(rx - lx, 0.0), ih = fmax(ry - ly, 0.0);
      double inter = iw * ih;
      double iou = inter / (areaA + areaB - inter + 1e-9);
      if (iou > 0.7) row[j >> 6] |= (1ull << (j & 63));
    }
#pragma unroll
    for (int w2 = 0; w2 < 8; ++w2) sh.b.mask[i][w2] = row[w2];
  }
  __syncthreads();

  if (tid == 0) {
    unsigned long long remv[8] = {0, 0, 0, 0, 0, 0, 0, 0};
    for (int i = 0; i < m; ++i) {
      if (!((remv[i >> 6] >> (i & 63)) & 1ull)) {
        sh.b.keep[i] = 1;
#pragma unroll
        for (int w2 = 0; w2 < 8; ++w2) remv[w2] |= sh.b.mask[i][w2];
      }
    }
  }
  __syncthreads();

  if (tid < 512) sh.b.ps[tid] = sh.b.keep[tid];
  __syncthreads();
  for (int o = 1; o < 512; o <<= 1) {
    int v = 0;
    if (tid < 512 && tid >= o) v = sh.b.ps[tid - o];
    __syncthreads();
    if (tid < 512) sh.b.ps[tid] += v;
    __syncthreads();
  }
  if (tid < 512 && sh.b.keep[tid]) {
    int pos = sh.b.ps[tid] - 1;
    const double* B = sh.b.bx[sh.b.idx[tid]];
    size_t gbase = (size_t)bid * 512 + pos;
#pragma unroll
    for (int q = 0; q < 4; q++) g_box[gbase * 4 + q] = B[q];
    g_u[gbase] = sh.b.u[tid];
  }
  if (tid == 0) g_cnt[bid] = (m > 0) ? sh.b.ps[511] : 0;
}

// ------- per-image select: 5-way merge of sorted kept lists, top 100 -----
__global__ __launch_bounds__(256) void select_kernel(
    const double* __restrict__ g_box, const unsigned long long* __restrict__ g_u,
    const int* __restrict__ g_cnt, float* __restrict__ out) {
  __shared__ unsigned long long s_u[5][512];
  __shared__ int s_pick[100];
  __shared__ int s_total;
  int n = blockIdx.x;
  int tid = threadIdx.x;
  int cnts[5];
#pragma unroll
  for (int l = 0; l < 5; l++) cnts[l] = g_cnt[n * 5 + l];
  for (int idx = tid; idx < 5 * 512; idx += 256) {
    int l = idx >> 9, r = idx & 511;
    s_u[l][r] = (r < cnts[l]) ? g_u[(size_t)(n * 5 + l) * 512 + r] : 0ull;
  }
  __syncthreads();
  if (tid == 0) {
    int hd[5] = {0, 0, 0, 0, 0};
    int t = 0;
    while (t < 100) {
      int bl = -1;
      unsigned long long bu = 0ull;
      for (int l = 0; l < 5; l++) {
        if (hd[l] < cnts[l] && s_u[l][hd[l]] > bu) {
          bu = s_u[l][hd[l]];
          bl = l;
        }
      }
      if (bl < 0) break;
      s_pick[t++] = bl * 512 + hd[bl];
      hd[bl]++;
    }
    s_total = t;
  }
  __syncthreads();
  int total = s_total;
  for (int t = tid; t < 100; t += 256) {
    if (t < total) {
      int pk = s_pick[t];
      int l = pk >> 9, r = pk & 511;
      size_t gbase = (size_t)(n * 5 + l) * 512 + r;
#pragma unroll
      for (int q = 0; q < 4; q++)
        out[(n * 100 + t) * 4 + q] = (float)g_box[gbase * 4 + q];
      out[800 + n * 100 + t] = (float)n;
    } else {
#pragma unroll
      for (int q = 0; q < 4; q++) out[(n * 100 + t) * 4 + q] = 0.0f;
      out[800 + n * 100 + t] = -1.0f;
    }
  }
}

extern "C" void kernel_launch(void* const* d_in, const int* in_sizes, int n_in,
                              void* d_out, int out_size, void* d_ws,
                              size_t ws_size, hipStream_t stream) {
  (void)in_sizes; (void)n_in; (void)out_size;
  const float* fmap[5];
  const float* priors[5];
  for (int l = 0; l < 5; l++) {
    fmap[l] = (const float*)d_in[2 * l];        // interleaved input order!
    priors[l] = (const float*)d_in[2 * l + 1];
  }
  const float* conv_w = (const float*)d_in[10];
  const float* conv_b = (const float*)d_in[11];
  const float* log_w = (const float*)d_in[12];
  const float* log_b = (const float*)d_in[13];
  const float* reg_w = (const float*)d_in[14];
  const float* reg_b = (const float*)d_in[15];
  const int* imsizes = (const int*)d_in[16];
  float* out = (float*)d_out;

  bool f64h = ws_size >= (size_t)66000000;

  char* base = (char*)d_ws;
  size_t off = 0;
  auto alloc = [&](size_t bytes) -> void* {
    off = (off + 255) & ~(size_t)255;
    void* p = base + off;
    off += bytes;
    return p;
  };
  double* wT2 = (double*)alloc(589824ull * 8);
  void* hraw = alloc(6831616ull * (f64h ? 8 : 4));
  double* logits = (double*)alloc(80058ull * 8);
  double* regs = (double*)alloc(320232ull * 8);
  double* g_box = (double*)alloc(10ull * 512 * 4 * 8);
  unsigned long long* g_u = (unsigned long long*)alloc(10ull * 512 * 8);
  int* g_cnt = (int*)alloc(10 * 4);

  transpose_w_kernel<<<2304, 256, 0, stream>>>(conv_w, wT2);

  if (f64h) {
    conv_fused_kernel<double><<<CONV_BLOCKS, 256, 0, stream>>>(
        fmap[0], fmap[1], fmap[2], fmap[3], fmap[4], wT2, conv_b,
        (double*)hraw);
    heads_fused_kernel<double><<<dim3(211, 2), 256, 0, stream>>>(
        (double*)hraw, log_w, log_b, reg_w, reg_b, logits, regs);
  } else {
    conv_fused_kernel<float><<<CONV_BLOCKS, 256, 0, stream>>>(
        fmap[0], fmap[1], fmap[2], fmap[3], fmap[4], wT2, conv_b,
        (float*)hraw);
    heads_fused_kernel<float><<<dim3(211, 2), 256, 0, stream>>>(
        (float*)hraw, log_w, log_b, reg_w, reg_b, logits, regs);
  }
  topk_nms_kernel<<<10, 1024, 0, stream>>>(
      logits, regs, priors[0], priors[1], priors[2], priors[3], priors[4],
      imsizes, g_box, g_u, g_cnt);
  select_kernel<<<2, 256, 0, stream>>>(g_box, g_u, g_cnt, out);
}

// Round 12
// 1075.553 us; speedup vs baseline: 1.1632x; 1.1632x over previous
//
#include <hip/hip_runtime.h>
#include <math.h>

// RPN forward: fused conv3x3+relu (f64 MFMA implicit GEMM, runtime
// layout-calibrated) -> fused 1x1 heads -> [topk+decode+sort+NMS+compact]
// (10 blocks) -> per-image 5-way merge select. 5 dispatches.
// Precision: f64 everywhere decision-relevant (absmax 0 through R2-R10).
// R11 FAIL: f64 MFMA fragment layout assumption wrong (documented H1 map
// failed). R12: self-calibrating probes — probe1 mfma(co-label, k0-ind)
// yields per-(lane,reg) co index; probe2 mfma(k0-ind, px-label) yields px
// index. Works under documented layout, operand-swap, or any D reg-spread
// (ERRATA #3 class). If this fails too, bug is not layout -> revert R9.

#define N_IMG 2
#define C_CH  256
#define D_PER 2147
#define K_TOT 4294
#define CONV_BLOCKS 1912
#define CPX 239              // CONV_BLOCKS / 8 XCDs (exact)

typedef double v4d __attribute__((ext_vector_type(4)));

__constant__ int c_Ml[5]     = {30000, 7500, 1875, 507, 147};
__constant__ int c_kl[5]     = {500, 500, 500, 500, 147};
__constant__ int c_logoff[5] = {0, 60000, 75000, 78750, 79764};   // 6*cumE
__constant__ int c_regoff[5] = {0, 240000, 300000, 315000, 319056}; // 24*cumE
__constant__ int c_fs[5]     = {100, 50, 25, 13, 7};
__constant__ int c_npt[5]    = {13, 7, 4, 2, 1};
__constant__ int c_E[5]      = {10000, 2500, 625, 169, 49};
__constant__ int c_cumbl[6]  = {0, 1352, 1744, 1872, 1904, 1912};
__constant__ int c_hcum[6]   = {0, 157, 197, 207, 210, 211};
__constant__ size_t c_hoff[5] = {0, 5120000, 6400000, 6720000, 6806528};

// ------- weight repack+convert: slabs of 2304 f64 = [tap9][ci4][co64] ----
__global__ void transpose_w_kernel(const float* __restrict__ w,
                                   double* __restrict__ wT2) {
  int i = blockIdx.x * 256 + threadIdx.x;
  if (i >= 589824) return;
  int q = i % 2304;
  int slab = i / 2304;
  int cobi = slab >> 6, ch = slab & 63;
  int tap = q / 256;
  int rem = q % 256;
  int ci = rem >> 6, co = rem & 63;
  wT2[i] =
      (double)w[(size_t)(cobi * 64 + co) * 2304 + (ch * 4 + ci) * 9 + tap];
}

// ------- fused conv3x3 (SAME) + bias + relu via f64 MFMA -----------------
// block: 256 thr = 4 waves; output tile 64co x 64px (8x8 spatial).
// wave wv owns co [16wv,16wv+16); 4 px-tiles of 16 px each.
// Supply convention: av = W[ci=lk][co-label=lx], bv = Im[ci=lk][px-label=lx].
// Epilogue uses probe-calibrated coL[r], pxL[r].
template <typename T>
__global__ __launch_bounds__(256) void conv_fused_kernel(
    const float* __restrict__ x0, const float* __restrict__ x1,
    const float* __restrict__ x2, const float* __restrict__ x3,
    const float* __restrict__ x4, const double* __restrict__ wT2,
    const float* __restrict__ bias, T* __restrict__ h) {
  __shared__ __align__(16) double s_in[4 * 120];  // [ci][10 rows x 12]
  __shared__ __align__(16) double s_w[2304];      // [tap][ci4][co64]
  int tid = threadIdx.x;
  int bid = (blockIdx.x & 7) * CPX + (blockIdx.x >> 3);  // XCD swizzle
  int l = 0;
  while (bid >= c_cumbl[l + 1]) ++l;
  int r = bid - c_cumbl[l];
  int fs = c_fs[l], npt = c_npt[l];
  int tiles = npt * npt;
  int tile = r % tiles;
  int cn = r / tiles;
  int cobi = cn & 3, n = cn >> 2;
  int ptx = tile % npt, pty = tile / npt;
  int px0 = ptx * 8, py0 = pty * 8;
  int E = fs * fs;
  const float* xl;
  switch (l) {
    case 0: xl = x0; break;
    case 1: xl = x1; break;
    case 2: xl = x2; break;
    case 3: xl = x3; break;
    default: xl = x4; break;
  }
  const float* xn = xl + (size_t)n * C_CH * E;
  T* hl = h + c_hoff[l];

  int lane = tid & 63;
  int wv = tid >> 6;            // wave id = co16 sub-tile
  int lx = lane & 15;           // label index (co for A-slot, px for B-slot)
  int lk = lane >> 4;           // k label (ci within chunk)

  // ---- layout calibration probes (2 MFMAs, ~free) ----
  // probe1: co-label on W-slot, k0-indicator on Im-slot -> D = co_local
  // probe2: k0-indicator on W-slot, px-label on Im-slot -> D = px_local
  double ind0 = (lk == 0) ? 1.0 : 0.0;
  v4d pr1 = __builtin_amdgcn_mfma_f64_16x16x4f64((double)lx, ind0,
                                                 (v4d)0.0, 0, 0, 0);
  v4d pr2 = __builtin_amdgcn_mfma_f64_16x16x4f64(ind0, (double)lx,
                                                 (v4d)0.0, 0, 0, 0);
  int coL[4], pxL[4];
#pragma unroll
  for (int q = 0; q < 4; ++q) {
    coL[q] = (int)pr1[q];
    pxL[q] = (int)pr2[q];
  }

  // staging descriptors: 400 halo elems over 256 thr
  int in_dst[2], in_src[2];
#pragma unroll
  for (int it = 0; it < 2; ++it) {
    int idx = tid + it * 256;
    in_dst[it] = -1;
    in_src[it] = -1;
    if (idx < 400) {
      int ci = idx / 100, rr2 = idx % 100;
      int hy = rr2 / 10, hx = rr2 % 10;
      int gy = py0 - 1 + hy, gx = px0 - 1 + hx;
      in_dst[it] = ci * 120 + hy * 12 + hx;
      if (gy >= 0 && gy < fs && gx >= 0 && gx < fs)
        in_src[it] = ci * E + gy * fs + gx;
    }
  }

  // lane-constant LDS bases (f64 units)
  const double* aBase = s_w + lk * 64 + wv * 16 + lx;   // + tap*256
  const double* bBase[4];
#pragma unroll
  for (int p = 0; p < 4; ++p) {
    int pxidx = p * 16 + lx;
    bBase[p] = s_in + lk * 120 + (pxidx >> 3) * 12 + (pxidx & 7);
  }

  v4d acc[4];
#pragma unroll
  for (int p = 0; p < 4; ++p) acc[p] = (v4d)0.0;

  const double2* wsrc0 = (const double2*)(wT2 + (size_t)cobi * 64 * 2304);

  for (int ch = 0; ch < 64; ++ch) {
    const float* xc = xn + (size_t)ch * 4 * E;
#pragma unroll
    for (int it = 0; it < 2; ++it) {
      if (in_dst[it] >= 0)
        s_in[in_dst[it]] = (in_src[it] >= 0) ? (double)xc[in_src[it]] : 0.0;
    }
    {
      const double2* src = wsrc0 + (size_t)ch * 1152;
      double2* dst = (double2*)s_w;
#pragma unroll
      for (int k = 0; k < 5; k++) {
        int idx = tid + k * 256;
        if (idx < 1152) dst[idx] = src[idx];
      }
    }
    __syncthreads();
#pragma unroll
    for (int ky = 0; ky < 3; ++ky) {
#pragma unroll
      for (int kx = 0; kx < 3; ++kx) {
        int tap = ky * 3 + kx;
        double av = aBase[tap * 256];
        int boff = ky * 12 + kx;
#pragma unroll
        for (int p = 0; p < 4; ++p) {
          double bv = bBase[p][boff];
          acc[p] = __builtin_amdgcn_mfma_f64_16x16x4f64(av, bv, acc[p],
                                                        0, 0, 0);
        }
      }
    }
    __syncthreads();
  }

  // epilogue: probe-calibrated (lane,reg) -> (co_local, px_local)
#pragma unroll
  for (int p = 0; p < 4; ++p) {
#pragma unroll
    for (int rr2 = 0; rr2 < 4; ++rr2) {
      int pxidx = p * 16 + pxL[rr2];
      int gy = py0 + (pxidx >> 3), gx = px0 + (pxidx & 7);
      int co = cobi * 64 + wv * 16 + coL[rr2];
      if (gy < fs && gx < fs) {
        double v = acc[p][rr2] + (double)bias[co];
        hl[((size_t)n * C_CH + co) * E + gy * fs + gx] = (T)fmax(v, 0.0);
      }
    }
  }
}

// ------- fused 1x1 heads: 64 px x 4 c-groups per block, LDS reduce -------
template <typename T>
__global__ __launch_bounds__(256) void heads_fused_kernel(
    const T* __restrict__ h, const float* __restrict__ logw,
    const float* __restrict__ logb, const float* __restrict__ regw,
    const float* __restrict__ regb, double* __restrict__ logits,
    double* __restrict__ regs) {
  __shared__ float s_wh[256][16];
  __shared__ double s_red[4][15][64];
  int tid = threadIdx.x;
  int n = blockIdx.y;
  int cidx = blockIdx.x;
  int l = 0;
  while (cidx >= c_hcum[l + 1]) ++l;
  int chunk = cidx - c_hcum[l];
  int E = c_E[l];
  int px0 = chunk * 64;
  const T* hl = h + c_hoff[l];
  double* logits_l = logits + c_logoff[l];
  double* regs_l = regs + c_regoff[l];

  for (int idx = tid; idx < 4096; idx += 256) {
    int c = idx >> 4, j = idx & 15;
    float v = 0.f;
    if (j < 3) v = logw[j * 256 + c];
    else if (j < 15) v = regw[(j - 3) * 256 + c];
    s_wh[c][j] = v;
  }
  __syncthreads();

  int p = tid & 63, c4 = tid >> 6;
  int pix = px0 + p;
  bool act = pix < E;
  double acc[15];
#pragma unroll
  for (int j = 0; j < 15; j++) acc[j] = 0.0;
  if (act) {
    const T* hp = hl + ((size_t)n * C_CH + c4 * 64) * E + pix;
    for (int cc = 0; cc < 64; ++cc) {
      double hv = (double)hp[(size_t)cc * E];
      const float* wr = &s_wh[c4 * 64 + cc][0];
#pragma unroll
      for (int j = 0; j < 15; j++)
        acc[j] = fma((double)wr[j], hv, acc[j]);
    }
  }
#pragma unroll
  for (int j = 0; j < 15; j++) s_red[c4][j][p] = acc[j];
  __syncthreads();
  if (act) {
    int M = E * 3;
    for (int j = c4; j < 15; j += 4) {
      double v = s_red[0][j][p] + s_red[1][j][p] + s_red[2][j][p] +
                 s_red[3][j][p];
      if (j < 3) {
        logits_l[(size_t)n * M + pix * 3 + j] = v + (double)logb[j];
      } else {
        int rj = j - 3, a = rj >> 2, coord = rj & 3;
        regs_l[((size_t)n * M + pix * 3 + a) * 4 + coord] =
            v + (double)regb[rj];
      }
    }
  }
}

// ------- topk + decode + per-group sort + NMS + compact (10 blocks) ------
__device__ __forceinline__ unsigned long long d2key(double v) {
  unsigned long long ub = (unsigned long long)__double_as_longlong(v);
  return (ub >> 63) ? ~ub : (ub | 0x8000000000000000ull);
}

#define TK_CH 30
union TkShared {
  struct {
    int histw[16][256];
    int hist[256];
    int sgt[1024];
    int seq[1024];
  } a;
  struct {
    unsigned long long u[512];
    int idx[512];
    int keep[512];
    int ps[512];
    int m;
    double bx[512][4];
    unsigned long long mask[512][8];
  } b;
};

__global__ __launch_bounds__(1024) void topk_nms_kernel(
    const double* __restrict__ logits, const double* __restrict__ regs,
    const float* __restrict__ p0, const float* __restrict__ p1,
    const float* __restrict__ p2, const float* __restrict__ p3,
    const float* __restrict__ p4, const int* __restrict__ imsizes,
    double* __restrict__ g_box, unsigned long long* __restrict__ g_u,
    int* __restrict__ g_cnt) {
  __shared__ TkShared sh;
  __shared__ int s_sel[512];
  __shared__ unsigned long long s_prefix;
  __shared__ int s_r;
  int bid = blockIdx.x;
  int n = bid / 5, l = bid % 5;
  int M = c_Ml[l], k = c_kl[l];
  const double* lg = logits + c_logoff[l] + (size_t)n * M;
  int tid = threadIdx.x;
  if (tid == 0) { s_prefix = 0ull; s_r = k; }

  int chunk = (M + 1023) >> 10;
  int i0 = tid * chunk, i1 = min(M, i0 + chunk);
  int cnt = i1 - i0;
  if (cnt < 0) cnt = 0;
  unsigned long long kv[TK_CH];
#pragma unroll
  for (int q = 0; q < TK_CH; q++)
    if (q < cnt) kv[q] = d2key(lg[i0 + q]);
  int wid = tid >> 6;
  __syncthreads();

  for (int pass = 0; pass < 8; ++pass) {
    int shift = 56 - pass * 8;
    for (int i = tid; i < 4096; i += 1024) ((int*)sh.a.histw)[i] = 0;
    __syncthreads();
    unsigned long long pfx = s_prefix;
    int rr = s_r;
#pragma unroll
    for (int q = 0; q < TK_CH; q++) {
      if (q < cnt) {
        unsigned long long u = kv[q];
        if (pass == 0 || (u >> (shift + 8)) == pfx)
          atomicAdd(&sh.a.histw[wid][(int)((u >> shift) & 255ull)], 1);
      }
    }
    __syncthreads();
    if (tid < 256) {
      int s = 0;
#pragma unroll
      for (int w = 0; w < 16; w++) s += sh.a.histw[w][tid];
      sh.a.hist[tid] = s;
    }
    __syncthreads();
    if (tid == 0) {
      int s = 0, beta = 0;
      for (int b = 255; b >= 0; --b) {
        if (s + sh.a.hist[b] >= rr) { beta = b; break; }
        s += sh.a.hist[b];
      }
      s_prefix = (pfx << 8) | (unsigned long long)beta;
      s_r = rr - s;
    }
    __syncthreads();
  }
  unsigned long long T = s_prefix;
  int need = s_r;
  int cgt = 0, ceq = 0;
#pragma unroll
  for (int q = 0; q < TK_CH; q++) {
    if (q < cnt) {
      cgt += (kv[q] > T);
      ceq += (kv[q] == T);
    }
  }
  sh.a.sgt[tid] = cgt;
  sh.a.seq[tid] = ceq;
  __syncthreads();
  for (int o = 1; o < 1024; o <<= 1) {
    int a = (tid >= o) ? sh.a.sgt[tid - o] : 0;
    int b2 = (tid >= o) ? sh.a.seq[tid - o] : 0;
    __syncthreads();
    sh.a.sgt[tid] += a;
    sh.a.seq[tid] += b2;
    __syncthreads();
  }
  int gt_total = sh.a.sgt[1023];
  int pg = sh.a.sgt[tid] - cgt, pe = sh.a.seq[tid] - ceq;
#pragma unroll
  for (int q = 0; q < TK_CH; q++) {
    if (q < cnt) {
      unsigned long long u = kv[q];
      if (u > T) {
        s_sel[pg++] = i0 + q;
      } else if (u == T) {
        if (pe < need) s_sel[gt_total + pe] = i0 + q;
        pe++;
      }
    }
  }
  __syncthreads();

  const float* pp;
  switch (l) {
    case 0: pp = p0; break;
    case 1: pp = p1; break;
    case 2: pp = p2; break;
    case 3: pp = p3; break;
    default: pp = p4; break;
  }
  const double* regs_l = regs + c_regoff[l];
  double imh = (double)imsizes[n * 2 + 0], imw = (double)imsizes[n * 2 + 1];
  const double BCLIP = 4.1351665567423560;
  if (tid < 512) {
    unsigned long long key = 0ull;
    sh.b.idx[tid] = tid;
    sh.b.keep[tid] = 0;
    if (tid < k) {
      int aidx = s_sel[tid];
      double lv = lg[aidx];
      double obj = 1.0 / (1.0 + exp(-lv));
      const double* rp = regs_l + ((size_t)n * M + aidx) * 4;
      const float* pr = pp + (size_t)aidx * 4;
      double px1 = pr[0], py1 = pr[1], px2 = pr[2], py2 = pr[3];
      double pw = px2 - px1, ph = py2 - py1;
      double pcx = px1 + 0.5 * pw, pcy = py1 + 0.5 * ph;
      double dx = rp[0], dy = rp[1];
      double dw = fmin(rp[2], BCLIP), dh = fmin(rp[3], BCLIP);
      double cx = dx * pw + pcx, cy = dy * ph + pcy;
      double w = exp(dw) * pw, hh = exp(dh) * ph;
      double x1 = cx - 0.5 * w, y1 = cy - 0.5 * hh;
      double x2 = cx + 0.5 * w, y2 = cy + 0.5 * hh;
      x1 = fmin(fmax(x1, 0.0), imw);
      x2 = fmin(fmax(x2, 0.0), imw);
      y1 = fmin(fmax(y1, 0.0), imh);
      y2 = fmin(fmax(y2, 0.0), imh);
      bool valid = (obj >= 0.5) && ((x2 - x1) >= 1.0) && ((y2 - y1) >= 1.0);
      sh.b.bx[tid][0] = x1;
      sh.b.bx[tid][1] = y1;
      sh.b.bx[tid][2] = x2;
      sh.b.bx[tid][3] = y2;
      if (valid) key = d2key(obj);
    }
    sh.b.u[tid] = key;
  }
  if (tid == 0) sh.b.m = 0;
  __syncthreads();

  for (int kk = 2; kk <= 512; kk <<= 1) {
    for (int j = kk >> 1; j > 0; j >>= 1) {
      if (tid < 512) {
        int i = tid, ixj = i ^ j;
        if (ixj > i) {
          unsigned long long ua = sh.b.u[i], ub = sh.b.u[ixj];
          int ia = sh.b.idx[i], ib = sh.b.idx[ixj];
          bool up = ((i & kk) == 0);
          bool aAfterB = (ua < ub) || (ua == ub && ia > ib);
          bool sw = up ? aAfterB : !aAfterB && (ua != ub || ia != ib);
          if (sw) {
            sh.b.u[i] = ub; sh.b.u[ixj] = ua;
            sh.b.idx[i] = ib; sh.b.idx[ixj] = ia;
          }
        }
      }
      __syncthreads();
    }
  }
  if (tid < 512) {
    if (sh.b.u[tid] != 0ull && (tid == 511 || sh.b.u[tid + 1] == 0ull))
      sh.b.m = tid + 1;
  }
  __syncthreads();
  int m = sh.b.m;

  if (tid < 512 && tid < m) {
    int i = tid;
    const double* A = sh.b.bx[sh.b.idx[i]];
    double ax1 = A[0], ay1 = A[1], ax2 = A[2], ay2 = A[3];
    double areaA = (ax2 - ax1) * (ay2 - ay1);
    unsigned long long row[8] = {0, 0, 0, 0, 0, 0, 0, 0};
    for (int j = i + 1; j < m; ++j) {
      const double* B = sh.b.bx[sh.b.idx[j]];
      double bx1 = B[0], by1 = B[1], bx2 = B[2], by2 = B[3];
      double areaB = (bx2 - bx1) * (by2 - by1);
      double lx = fmax(ax1, bx1), ly = fmax(ay1, by1);
      double rx = fmin(ax2, bx2), ry = fmin(ay2, by2);
      double iw = fmax(rx - lx, 0.0), ih = fmax(ry - ly, 0.0);
      double inter = iw * ih;
      double iou = inter / (areaA + areaB - inter + 1e-9);
      if (iou > 0.7) row[j >> 6] |= (1ull << (j & 63));
    }
#pragma unroll
    for (int w2 = 0; w2 < 8; ++w2) sh.b.mask[i][w2] = row[w2];
  }
  __syncthreads();

  if (tid == 0) {
    unsigned long long remv[8] = {0, 0, 0, 0, 0, 0, 0, 0};
    for (int i = 0; i < m; ++i) {
      if (!((remv[i >> 6] >> (i & 63)) & 1ull)) {
        sh.b.keep[i] = 1;
#pragma unroll
        for (int w2 = 0; w2 < 8; ++w2) remv[w2] |= sh.b.mask[i][w2];
      }
    }
  }
  __syncthreads();

  if (tid < 512) sh.b.ps[tid] = sh.b.keep[tid];
  __syncthreads();
  for (int o = 1; o < 512; o <<= 1) {
    int v = 0;
    if (tid < 512 && tid >= o) v = sh.b.ps[tid - o];
    __syncthreads();
    if (tid < 512) sh.b.ps[tid] += v;
    __syncthreads();
  }
  if (tid < 512 && sh.b.keep[tid]) {
    int pos = sh.b.ps[tid] - 1;
    const double* B = sh.b.bx[sh.b.idx[tid]];
    size_t gbase = (size_t)bid * 512 + pos;
#pragma unroll
    for (int q = 0; q < 4; q++) g_box[gbase * 4 + q] = B[q];
    g_u[gbase] = sh.b.u[tid];
  }
  if (tid == 0) g_cnt[bid] = (m > 0) ? sh.b.ps[511] : 0;
}

// ------- per-image select: 5-way merge of sorted kept lists, top 100 -----
__global__ __launch_bounds__(256) void select_kernel(
    const double* __restrict__ g_box, const unsigned long long* __restrict__ g_u,
    const int* __restrict__ g_cnt, float* __restrict__ out) {
  __shared__ unsigned long long s_u[5][512];
  __shared__ int s_pick[100];
  __shared__ int s_total;
  int n = blockIdx.x;
  int tid = threadIdx.x;
  int cnts[5];
#pragma unroll
  for (int l = 0; l < 5; l++) cnts[l] = g_cnt[n * 5 + l];
  for (int idx = tid; idx < 5 * 512; idx += 256) {
    int l = idx >> 9, r = idx & 511;
    s_u[l][r] = (r < cnts[l]) ? g_u[(size_t)(n * 5 + l) * 512 + r] : 0ull;
  }
  __syncthreads();
  if (tid == 0) {
    int hd[5] = {0, 0, 0, 0, 0};
    int t = 0;
    while (t < 100) {
      int bl = -1;
      unsigned long long bu = 0ull;
      for (int l = 0; l < 5; l++) {
        if (hd[l] < cnts[l] && s_u[l][hd[l]] > bu) {
          bu = s_u[l][hd[l]];
          bl = l;
        }
      }
      if (bl < 0) break;
      s_pick[t++] = bl * 512 + hd[bl];
      hd[bl]++;
    }
    s_total = t;
  }
  __syncthreads();
  int total = s_total;
  for (int t = tid; t < 100; t += 256) {
    if (t < total) {
      int pk = s_pick[t];
      int l = pk >> 9, r = pk & 511;
      size_t gbase = (size_t)(n * 5 + l) * 512 + r;
#pragma unroll
      for (int q = 0; q < 4; q++)
        out[(n * 100 + t) * 4 + q] = (float)g_box[gbase * 4 + q];
      out[800 + n * 100 + t] = (float)n;
    } else {
#pragma unroll
      for (int q = 0; q < 4; q++) out[(n * 100 + t) * 4 + q] = 0.0f;
      out[800 + n * 100 + t] = -1.0f;
    }
  }
}

extern "C" void kernel_launch(void* const* d_in, const int* in_sizes, int n_in,
                              void* d_out, int out_size, void* d_ws,
                              size_t ws_size, hipStream_t stream) {
  (void)in_sizes; (void)n_in; (void)out_size;
  const float* fmap[5];
  const float* priors[5];
  for (int l = 0; l < 5; l++) {
    fmap[l] = (const float*)d_in[2 * l];        // interleaved input order!
    priors[l] = (const float*)d_in[2 * l + 1];
  }
  const float* conv_w = (const float*)d_in[10];
  const float* conv_b = (const float*)d_in[11];
  const float* log_w = (const float*)d_in[12];
  const float* log_b = (const float*)d_in[13];
  const float* reg_w = (const float*)d_in[14];
  const float* reg_b = (const float*)d_in[15];
  const int* imsizes = (const int*)d_in[16];
  float* out = (float*)d_out;

  bool f64h = ws_size >= (size_t)66000000;

  char* base = (char*)d_ws;
  size_t off = 0;
  auto alloc = [&](size_t bytes) -> void* {
    off = (off + 255) & ~(size_t)255;
    void* p = base + off;
    off += bytes;
    return p;
  };
  double* wT2 = (double*)alloc(589824ull * 8);
  void* hraw = alloc(6831616ull * (f64h ? 8 : 4));
  double* logits = (double*)alloc(80058ull * 8);
  double* regs = (double*)alloc(320232ull * 8);
  double* g_box = (double*)alloc(10ull * 512 * 4 * 8);
  unsigned long long* g_u = (unsigned long long*)alloc(10ull * 512 * 8);
  int* g_cnt = (int*)alloc(10 * 4);

  transpose_w_kernel<<<2304, 256, 0, stream>>>(conv_w, wT2);

  if (f64h) {
    conv_fused_kernel<double><<<CONV_BLOCKS, 256, 0, stream>>>(
        fmap[0], fmap[1], fmap[2], fmap[3], fmap[4], wT2, conv_b,
        (double*)hraw);
    heads_fused_kernel<double><<<dim3(211, 2), 256, 0, stream>>>(
        (double*)hraw, log_w, log_b, reg_w, reg_b, logits, regs);
  } else {
    conv_fused_kernel<float><<<CONV_BLOCKS, 256, 0, stream>>>(
        fmap[0], fmap[1], fmap[2], fmap[3], fmap[4], wT2, conv_b,
        (float*)hraw);
    heads_fused_kernel<float><<<dim3(211, 2), 256, 0, stream>>>(
        (float*)hraw, log_w, log_b, reg_w, reg_b, logits, regs);
  }
  topk_nms_kernel<<<10, 1024, 0, stream>>>(
      logits, regs, priors[0], priors[1], priors[2], priors[3], priors[4],
      imsizes, g_box, g_u, g_cnt);
  select_kernel<<<2, 256, 0, stream>>>(g_box, g_u, g_cnt, out);
}

// Round 13
// 1034.527 us; speedup vs baseline: 1.2094x; 1.0397x over previous
//
#include <hip/hip_runtime.h>
#include <math.h>

// RPN forward: fused conv3x3+relu (f64 MFMA implicit GEMM, layout-probed,
// reg-weights + dbuf input LDS) -> fused 1x1 heads ->
// [topk+decode+sort+NMS+compact] (10 blocks) -> per-image merge select.
// Precision: f64 everywhere decision-relevant (absmax 0 through R12).
// R12: MFMA conv 764us, MfmaUtil 65%, VALU 13.5% -> 35% pipe-idle = weight
// LDS round-trip (18KB/chunk + 2 barriers). R13: weights global->VGPR
// (9 f64/lane/chunk, prefetched 1 chunk ahead, L2-hot via XCD swizzle);
// input halo double-buffered in LDS (7.7KB total), 1 barrier/chunk.
// MFMA floor 460us; target ~500-550.

#define N_IMG 2
#define C_CH  256
#define D_PER 2147
#define K_TOT 4294
#define CONV_BLOCKS 1912
#define CPX 239              // CONV_BLOCKS / 8 XCDs (exact)

typedef double v4d __attribute__((ext_vector_type(4)));

__constant__ int c_Ml[5]     = {30000, 7500, 1875, 507, 147};
__constant__ int c_kl[5]     = {500, 500, 500, 500, 147};
__constant__ int c_logoff[5] = {0, 60000, 75000, 78750, 79764};   // 6*cumE
__constant__ int c_regoff[5] = {0, 240000, 300000, 315000, 319056}; // 24*cumE
__constant__ int c_fs[5]     = {100, 50, 25, 13, 7};
__constant__ int c_npt[5]    = {13, 7, 4, 2, 1};
__constant__ int c_E[5]      = {10000, 2500, 625, 169, 49};
__constant__ int c_cumbl[6]  = {0, 1352, 1744, 1872, 1904, 1912};
__constant__ int c_hcum[6]   = {0, 157, 197, 207, 210, 211};
__constant__ size_t c_hoff[5] = {0, 5120000, 6400000, 6720000, 6806528};

// ------- weight repack+convert: slabs of 2304 f64 = [tap9][ci4][co64] ----
__global__ void transpose_w_kernel(const float* __restrict__ w,
                                   double* __restrict__ wT2) {
  int i = blockIdx.x * 256 + threadIdx.x;
  if (i >= 589824) return;
  int q = i % 2304;
  int slab = i / 2304;
  int cobi = slab >> 6, ch = slab & 63;
  int tap = q / 256;
  int rem = q % 256;
  int ci = rem >> 6, co = rem & 63;
  wT2[i] =
      (double)w[(size_t)(cobi * 64 + co) * 2304 + (ch * 4 + ci) * 9 + tap];
}

// ------- fused conv3x3 (SAME) + bias + relu via f64 MFMA -----------------
// block: 256 thr = 4 waves; tile 64co x 64px (8x8). wave wv: co16 group.
// A-operand (weights) from registers, prefetched; B from dbuf LDS halo.
template <typename T>
__global__ __launch_bounds__(256) void conv_fused_kernel(
    const float* __restrict__ x0, const float* __restrict__ x1,
    const float* __restrict__ x2, const float* __restrict__ x3,
    const float* __restrict__ x4, const double* __restrict__ wT2,
    const float* __restrict__ bias, T* __restrict__ h) {
  __shared__ __align__(16) double s_in[2 * 480];  // dbuf [ci4][10x12]
  int tid = threadIdx.x;
  int bid = (blockIdx.x & 7) * CPX + (blockIdx.x >> 3);  // XCD swizzle
  int l = 0;
  while (bid >= c_cumbl[l + 1]) ++l;
  int r = bid - c_cumbl[l];
  int fs = c_fs[l], npt = c_npt[l];
  int tiles = npt * npt;
  int tile = r % tiles;
  int cn = r / tiles;
  int cobi = cn & 3, n = cn >> 2;
  int ptx = tile % npt, pty = tile / npt;
  int px0 = ptx * 8, py0 = pty * 8;
  int E = fs * fs;
  const float* xl;
  switch (l) {
    case 0: xl = x0; break;
    case 1: xl = x1; break;
    case 2: xl = x2; break;
    case 3: xl = x3; break;
    default: xl = x4; break;
  }
  const float* xn = xl + (size_t)n * C_CH * E;
  T* hl = h + c_hoff[l];

  int lane = tid & 63;
  int wv = tid >> 6;
  int lx = lane & 15;
  int lk = lane >> 4;

  // ---- layout calibration probes (verified R12) ----
  double ind0 = (lk == 0) ? 1.0 : 0.0;
  v4d pr1 = __builtin_amdgcn_mfma_f64_16x16x4f64((double)lx, ind0,
                                                 (v4d)0.0, 0, 0, 0);
  v4d pr2 = __builtin_amdgcn_mfma_f64_16x16x4f64(ind0, (double)lx,
                                                 (v4d)0.0, 0, 0, 0);
  int coL[4], pxL[4];
#pragma unroll
  for (int q = 0; q < 4; ++q) {
    coL[q] = (int)pr1[q];
    pxL[q] = (int)pr2[q];
  }

  // staging descriptors: 400 halo elems over 256 thr (2 slots)
  int in_dst[2], in_src[2];
#pragma unroll
  for (int it = 0; it < 2; ++it) {
    int idx = tid + it * 256;
    in_dst[it] = -1;
    in_src[it] = -1;
    if (idx < 400) {
      int ci = idx / 100, rr2 = idx % 100;
      int hy = rr2 / 10, hx = rr2 % 10;
      int gy = py0 - 1 + hy, gx = px0 - 1 + hx;
      in_dst[it] = ci * 120 + hy * 12 + hx;
      if (gy >= 0 && gy < fs && gx >= 0 && gx < fs)
        in_src[it] = ci * E + gy * fs + gx;
    }
  }

  // per-lane B offsets within one buffer
  int bOff[4];
#pragma unroll
  for (int p = 0; p < 4; ++p) {
    int pxidx = p * 16 + lx;
    bOff[p] = lk * 120 + (pxidx >> 3) * 12 + (pxidx & 7);
  }

  v4d acc[4];
#pragma unroll
  for (int p = 0; p < 4; ++p) acc[p] = (v4d)0.0;

  // per-lane weight pointer: wT2[cobi slab] + lane offset; +2304/chunk
  const double* wptr =
      wT2 + (size_t)cobi * 64 * 2304 + lk * 64 + wv * 16 + lx;

  double wcur[9], wnxt[9];
#pragma unroll
  for (int t = 0; t < 9; ++t) wcur[t] = wptr[t * 256];
  {
    float v0[2];
#pragma unroll
    for (int it = 0; it < 2; ++it)
      v0[it] = (in_dst[it] >= 0 && in_src[it] >= 0) ? xn[in_src[it]] : 0.f;
#pragma unroll
    for (int it = 0; it < 2; ++it)
      if (in_dst[it] >= 0) s_in[in_dst[it]] = (double)v0[it];
  }
  __syncthreads();

  for (int ch = 0; ch < 64; ++ch) {
    int buf = ch & 1;
    bool more = (ch + 1 < 64);
    float inx[2];
    if (more) {
      const float* xc1 = xn + (size_t)(ch + 1) * 4 * E;
#pragma unroll
      for (int it = 0; it < 2; ++it)
        inx[it] =
            (in_dst[it] >= 0 && in_src[it] >= 0) ? xc1[in_src[it]] : 0.f;
      const double* wn = wptr + 2304;
#pragma unroll
      for (int t = 0; t < 9; ++t) wnxt[t] = wn[t * 256];
    }
    const double* bb = s_in + buf * 480;
#pragma unroll
    for (int ky = 0; ky < 3; ++ky) {
#pragma unroll
      for (int kx = 0; kx < 3; ++kx) {
        int tap = ky * 3 + kx;
        double av = wcur[tap];
        int boff = ky * 12 + kx;
#pragma unroll
        for (int p = 0; p < 4; ++p) {
          double bv = bb[bOff[p] + boff];
          acc[p] = __builtin_amdgcn_mfma_f64_16x16x4f64(av, bv, acc[p],
                                                        0, 0, 0);
        }
      }
    }
    if (more) {
      double* db = s_in + (buf ^ 1) * 480;
#pragma unroll
      for (int it = 0; it < 2; ++it)
        if (in_dst[it] >= 0) db[in_dst[it]] = (double)inx[it];
#pragma unroll
      for (int t = 0; t < 9; ++t) wcur[t] = wnxt[t];
    }
    __syncthreads();
    wptr += 2304;
  }

  // epilogue: probe-calibrated (lane,reg) -> (co_local, px_local)
#pragma unroll
  for (int p = 0; p < 4; ++p) {
#pragma unroll
    for (int rr2 = 0; rr2 < 4; ++rr2) {
      int pxidx = p * 16 + pxL[rr2];
      int gy = py0 + (pxidx >> 3), gx = px0 + (pxidx & 7);
      int co = cobi * 64 + wv * 16 + coL[rr2];
      if (gy < fs && gx < fs) {
        double v = acc[p][rr2] + (double)bias[co];
        hl[((size_t)n * C_CH + co) * E + gy * fs + gx] = (T)fmax(v, 0.0);
      }
    }
  }
}

// ------- fused 1x1 heads: 64 px x 4 c-groups per block, LDS reduce -------
template <typename T>
__global__ __launch_bounds__(256) void heads_fused_kernel(
    const T* __restrict__ h, const float* __restrict__ logw,
    const float* __restrict__ logb, const float* __restrict__ regw,
    const float* __restrict__ regb, double* __restrict__ logits,
    double* __restrict__ regs) {
  __shared__ float s_wh[256][16];
  __shared__ double s_red[4][15][64];
  int tid = threadIdx.x;
  int n = blockIdx.y;
  int cidx = blockIdx.x;
  int l = 0;
  while (cidx >= c_hcum[l + 1]) ++l;
  int chunk = cidx - c_hcum[l];
  int E = c_E[l];
  int px0 = chunk * 64;
  const T* hl = h + c_hoff[l];
  double* logits_l = logits + c_logoff[l];
  double* regs_l = regs + c_regoff[l];

  for (int idx = tid; idx < 4096; idx += 256) {
    int c = idx >> 4, j = idx & 15;
    float v = 0.f;
    if (j < 3) v = logw[j * 256 + c];
    else if (j < 15) v = regw[(j - 3) * 256 + c];
    s_wh[c][j] = v;
  }
  __syncthreads();

  int p = tid & 63, c4 = tid >> 6;
  int pix = px0 + p;
  bool act = pix < E;
  double acc[15];
#pragma unroll
  for (int j = 0; j < 15; j++) acc[j] = 0.0;
  if (act) {
    const T* hp = hl + ((size_t)n * C_CH + c4 * 64) * E + pix;
    for (int cc = 0; cc < 64; ++cc) {
      double hv = (double)hp[(size_t)cc * E];
      const float* wr = &s_wh[c4 * 64 + cc][0];
#pragma unroll
      for (int j = 0; j < 15; j++)
        acc[j] = fma((double)wr[j], hv, acc[j]);
    }
  }
#pragma unroll
  for (int j = 0; j < 15; j++) s_red[c4][j][p] = acc[j];
  __syncthreads();
  if (act) {
    int M = E * 3;
    for (int j = c4; j < 15; j += 4) {
      double v = s_red[0][j][p] + s_red[1][j][p] + s_red[2][j][p] +
                 s_red[3][j][p];
      if (j < 3) {
        logits_l[(size_t)n * M + pix * 3 + j] = v + (double)logb[j];
      } else {
        int rj = j - 3, a = rj >> 2, coord = rj & 3;
        regs_l[((size_t)n * M + pix * 3 + a) * 4 + coord] =
            v + (double)regb[rj];
      }
    }
  }
}

// ------- topk + decode + per-group sort + NMS + compact (10 blocks) ------
__device__ __forceinline__ unsigned long long d2key(double v) {
  unsigned long long ub = (unsigned long long)__double_as_longlong(v);
  return (ub >> 63) ? ~ub : (ub | 0x8000000000000000ull);
}

#define TK_CH 30
union TkShared {
  struct {
    int histw[16][256];
    int hist[256];
    int sgt[1024];
    int seq[1024];
  } a;
  struct {
    unsigned long long u[512];
    int idx[512];
    int keep[512];
    int ps[512];
    int m;
    double bx[512][4];
    unsigned long long mask[512][8];
  } b;
};

__global__ __launch_bounds__(1024) void topk_nms_kernel(
    const double* __restrict__ logits, const double* __restrict__ regs,
    const float* __restrict__ p0, const float* __restrict__ p1,
    const float* __restrict__ p2, const float* __restrict__ p3,
    const float* __restrict__ p4, const int* __restrict__ imsizes,
    double* __restrict__ g_box, unsigned long long* __restrict__ g_u,
    int* __restrict__ g_cnt) {
  __shared__ TkShared sh;
  __shared__ int s_sel[512];
  __shared__ unsigned long long s_prefix;
  __shared__ int s_r;
  int bid = blockIdx.x;
  int n = bid / 5, l = bid % 5;
  int M = c_Ml[l], k = c_kl[l];
  const double* lg = logits + c_logoff[l] + (size_t)n * M;
  int tid = threadIdx.x;
  if (tid == 0) { s_prefix = 0ull; s_r = k; }

  int chunk = (M + 1023) >> 10;
  int i0 = tid * chunk, i1 = min(M, i0 + chunk);
  int cnt = i1 - i0;
  if (cnt < 0) cnt = 0;
  unsigned long long kv[TK_CH];
#pragma unroll
  for (int q = 0; q < TK_CH; q++)
    if (q < cnt) kv[q] = d2key(lg[i0 + q]);
  int wid = tid >> 6;
  __syncthreads();

  for (int pass = 0; pass < 8; ++pass) {
    int shift = 56 - pass * 8;
    for (int i = tid; i < 4096; i += 1024) ((int*)sh.a.histw)[i] = 0;
    __syncthreads();
    unsigned long long pfx = s_prefix;
    int rr = s_r;
#pragma unroll
    for (int q = 0; q < TK_CH; q++) {
      if (q < cnt) {
        unsigned long long u = kv[q];
        if (pass == 0 || (u >> (shift + 8)) == pfx)
          atomicAdd(&sh.a.histw[wid][(int)((u >> shift) & 255ull)], 1);
      }
    }
    __syncthreads();
    if (tid < 256) {
      int s = 0;
#pragma unroll
      for (int w = 0; w < 16; w++) s += sh.a.histw[w][tid];
      sh.a.hist[tid] = s;
    }
    __syncthreads();
    if (tid == 0) {
      int s = 0, beta = 0;
      for (int b = 255; b >= 0; --b) {
        if (s + sh.a.hist[b] >= rr) { beta = b; break; }
        s += sh.a.hist[b];
      }
      s_prefix = (pfx << 8) | (unsigned long long)beta;
      s_r = rr - s;
    }
    __syncthreads();
  }
  unsigned long long T = s_prefix;
  int need = s_r;
  int cgt = 0, ceq = 0;
#pragma unroll
  for (int q = 0; q < TK_CH; q++) {
    if (q < cnt) {
      cgt += (kv[q] > T);
      ceq += (kv[q] == T);
    }
  }
  sh.a.sgt[tid] = cgt;
  sh.a.seq[tid] = ceq;
  __syncthreads();
  for (int o = 1; o < 1024; o <<= 1) {
    int a = (tid >= o) ? sh.a.sgt[tid - o] : 0;
    int b2 = (tid >= o) ? sh.a.seq[tid - o] : 0;
    __syncthreads();
    sh.a.sgt[tid] += a;
    sh.a.seq[tid] += b2;
    __syncthreads();
  }
  int gt_total = sh.a.sgt[1023];
  int pg = sh.a.sgt[tid] - cgt, pe = sh.a.seq[tid] - ceq;
#pragma unroll
  for (int q = 0; q < TK_CH; q++) {
    if (q < cnt) {
      unsigned long long u = kv[q];
      if (u > T) {
        s_sel[pg++] = i0 + q;
      } else if (u == T) {
        if (pe < need) s_sel[gt_total + pe] = i0 + q;
        pe++;
      }
    }
  }
  __syncthreads();

  const float* pp;
  switch (l) {
    case 0: pp = p0; break;
    case 1: pp = p1; break;
    case 2: pp = p2; break;
    case 3: pp = p3; break;
    default: pp = p4; break;
  }
  const double* regs_l = regs + c_regoff[l];
  double imh = (double)imsizes[n * 2 + 0], imw = (double)imsizes[n * 2 + 1];
  const double BCLIP = 4.1351665567423560;
  if (tid < 512) {
    unsigned long long key = 0ull;
    sh.b.idx[tid] = tid;
    sh.b.keep[tid] = 0;
    if (tid < k) {
      int aidx = s_sel[tid];
      double lv = lg[aidx];
      double obj = 1.0 / (1.0 + exp(-lv));
      const double* rp = regs_l + ((size_t)n * M + aidx) * 4;
      const float* pr = pp + (size_t)aidx * 4;
      double px1 = pr[0], py1 = pr[1], px2 = pr[2], py2 = pr[3];
      double pw = px2 - px1, ph = py2 - py1;
      double pcx = px1 + 0.5 * pw, pcy = py1 + 0.5 * ph;
      double dx = rp[0], dy = rp[1];
      double dw = fmin(rp[2], BCLIP), dh = fmin(rp[3], BCLIP);
      double cx = dx * pw + pcx, cy = dy * ph + pcy;
      double w = exp(dw) * pw, hh = exp(dh) * ph;
      double x1 = cx - 0.5 * w, y1 = cy - 0.5 * hh;
      double x2 = cx + 0.5 * w, y2 = cy + 0.5 * hh;
      x1 = fmin(fmax(x1, 0.0), imw);
      x2 = fmin(fmax(x2, 0.0), imw);
      y1 = fmin(fmax(y1, 0.0), imh);
      y2 = fmin(fmax(y2, 0.0), imh);
      bool valid = (obj >= 0.5) && ((x2 - x1) >= 1.0) && ((y2 - y1) >= 1.0);
      sh.b.bx[tid][0] = x1;
      sh.b.bx[tid][1] = y1;
      sh.b.bx[tid][2] = x2;
      sh.b.bx[tid][3] = y2;
      if (valid) key = d2key(obj);
    }
    sh.b.u[tid] = key;
  }
  if (tid == 0) sh.b.m = 0;
  __syncthreads();

  for (int kk = 2; kk <= 512; kk <<= 1) {
    for (int j = kk >> 1; j > 0; j >>= 1) {
      if (tid < 512) {
        int i = tid, ixj = i ^ j;
        if (ixj > i) {
          unsigned long long ua = sh.b.u[i], ub = sh.b.u[ixj];
          int ia = sh.b.idx[i], ib = sh.b.idx[ixj];
          bool up = ((i & kk) == 0);
          bool aAfterB = (ua < ub) || (ua == ub && ia > ib);
          bool sw = up ? aAfterB : !aAfterB && (ua != ub || ia != ib);
          if (sw) {
            sh.b.u[i] = ub; sh.b.u[ixj] = ua;
            sh.b.idx[i] = ib; sh.b.idx[ixj] = ia;
          }
        }
      }
      __syncthreads();
    }
  }
  if (tid < 512) {
    if (sh.b.u[tid] != 0ull && (tid == 511 || sh.b.u[tid + 1] == 0ull))
      sh.b.m = tid + 1;
  }
  __syncthreads();
  int m = sh.b.m;

  if (tid < 512 && tid < m) {
    int i = tid;
    const double* A = sh.b.bx[sh.b.idx[i]];
    double ax1 = A[0], ay1 = A[1], ax2 = A[2], ay2 = A[3];
    double areaA = (ax2 - ax1) * (ay2 - ay1);
    unsigned long long row[8] = {0, 0, 0, 0, 0, 0, 0, 0};
    for (int j = i + 1; j < m; ++j) {
      const double* B = sh.b.bx[sh.b.idx[j]];
      double bx1 = B[0], by1 = B[1], bx2 = B[2], by2 = B[3];
      double areaB = (bx2 - bx1) * (by2 - by1);
      double lx = fmax(ax1, bx1), ly = fmax(ay1, by1);
      double rx = fmin(ax2, bx2), ry = fmin(ay2, by2);
      double iw = fmax(rx - lx, 0.0), ih = fmax(ry - ly, 0.0);
      double inter = iw * ih;
      double iou = inter / (areaA + areaB - inter + 1e-9);
      if (iou > 0.7) row[j >> 6] |= (1ull << (j & 63));
    }
#pragma unroll
    for (int w2 = 0; w2 < 8; ++w2) sh.b.mask[i][w2] = row[w2];
  }
  __syncthreads();

  if (tid == 0) {
    unsigned long long remv[8] = {0, 0, 0, 0, 0, 0, 0, 0};
    for (int i = 0; i < m; ++i) {
      if (!((remv[i >> 6] >> (i & 63)) & 1ull)) {
        sh.b.keep[i] = 1;
#pragma unroll
        for (int w2 = 0; w2 < 8; ++w2) remv[w2] |= sh.b.mask[i][w2];
      }
    }
  }
  __syncthreads();

  if (tid < 512) sh.b.ps[tid] = sh.b.keep[tid];
  __syncthreads();
  for (int o = 1; o < 512; o <<= 1) {
    int v = 0;
    if (tid < 512 && tid >= o) v = sh.b.ps[tid - o];
    __syncthreads();
    if (tid < 512) sh.b.ps[tid] += v;
    __syncthreads();
  }
  if (tid < 512 && sh.b.keep[tid]) {
    int pos = sh.b.ps[tid] - 1;
    const double* B = sh.b.bx[sh.b.idx[tid]];
    size_t gbase = (size_t)bid * 512 + pos;
#pragma unroll
    for (int q = 0; q < 4; q++) g_box[gbase * 4 + q] = B[q];
    g_u[gbase] = sh.b.u[tid];
  }
  if (tid == 0) g_cnt[bid] = (m > 0) ? sh.b.ps[511] : 0;
}

// ------- per-image select: 5-way merge of sorted kept lists, top 100 -----
__global__ __launch_bounds__(256) void select_kernel(
    const double* __restrict__ g_box, const unsigned long long* __restrict__ g_u,
    const int* __restrict__ g_cnt, float* __restrict__ out) {
  __shared__ unsigned long long s_u[5][512];
  __shared__ int s_pick[100];
  __shared__ int s_total;
  int n = blockIdx.x;
  int tid = threadIdx.x;
  int cnts[5];
#pragma unroll
  for (int l = 0; l < 5; l++) cnts[l] = g_cnt[n * 5 + l];
  for (int idx = tid; idx < 5 * 512; idx += 256) {
    int l = idx >> 9, r = idx & 511;
    s_u[l][r] = (r < cnts[l]) ? g_u[(size_t)(n * 5 + l) * 512 + r] : 0ull;
  }
  __syncthreads();
  if (tid == 0) {
    int hd[5] = {0, 0, 0, 0, 0};
    int t = 0;
    while (t < 100) {
      int bl = -1;
      unsigned long long bu = 0ull;
      for (int l = 0; l < 5; l++) {
        if (hd[l] < cnts[l] && s_u[l][hd[l]] > bu) {
          bu = s_u[l][hd[l]];
          bl = l;
        }
      }
      if (bl < 0) break;
      s_pick[t++] = bl * 512 + hd[bl];
      hd[bl]++;
    }
    s_total = t;
  }
  __syncthreads();
  int total = s_total;
  for (int t = tid; t < 100; t += 256) {
    if (t < total) {
      int pk = s_pick[t];
      int l = pk >> 9, r = pk & 511;
      size_t gbase = (size_t)(n * 5 + l) * 512 + r;
#pragma unroll
      for (int q = 0; q < 4; q++)
        out[(n * 100 + t) * 4 + q] = (float)g_box[gbase * 4 + q];
      out[800 + n * 100 + t] = (float)n;
    } else {
#pragma unroll
      for (int q = 0; q < 4; q++) out[(n * 100 + t) * 4 + q] = 0.0f;
      out[800 + n * 100 + t] = -1.0f;
    }
  }
}

extern "C" void kernel_launch(void* const* d_in, const int* in_sizes, int n_in,
                              void* d_out, int out_size, void* d_ws,
                              size_t ws_size, hipStream_t stream) {
  (void)in_sizes; (void)n_in; (void)out_size;
  const float* fmap[5];
  const float* priors[5];
  for (int l = 0; l < 5; l++) {
    fmap[l] = (const float*)d_in[2 * l];        // interleaved input order!
    priors[l] = (const float*)d_in[2 * l + 1];
  }
  const float* conv_w = (const float*)d_in[10];
  const float* conv_b = (const float*)d_in[11];
  const float* log_w = (const float*)d_in[12];
  const float* log_b = (const float*)d_in[13];
  const float* reg_w = (const float*)d_in[14];
  const float* reg_b = (const float*)d_in[15];
  const int* imsizes = (const int*)d_in[16];
  float* out = (float*)d_out;

  bool f64h = ws_size >= (size_t)66000000;

  char* base = (char*)d_ws;
  size_t off = 0;
  auto alloc = [&](size_t bytes) -> void* {
    off = (off + 255) & ~(size_t)255;
    void* p = base + off;
    off += bytes;
    return p;
  };
  double* wT2 = (double*)alloc(589824ull * 8);
  void* hraw = alloc(6831616ull * (f64h ? 8 : 4));
  double* logits = (double*)alloc(80058ull * 8);
  double* regs = (double*)alloc(320232ull * 8);
  double* g_box = (double*)alloc(10ull * 512 * 4 * 8);
  unsigned long long* g_u = (unsigned long long*)alloc(10ull * 512 * 8);
  int* g_cnt = (int*)alloc(10 * 4);

  transpose_w_kernel<<<2304, 256, 0, stream>>>(conv_w, wT2);

  if (f64h) {
    conv_fused_kernel<double><<<CONV_BLOCKS, 256, 0, stream>>>(
        fmap[0], fmap[1], fmap[2], fmap[3], fmap[4], wT2, conv_b,
        (double*)hraw);
    heads_fused_kernel<double><<<dim3(211, 2), 256, 0, stream>>>(
        (double*)hraw, log_w, log_b, reg_w, reg_b, logits, regs);
  } else {
    conv_fused_kernel<float><<<CONV_BLOCKS, 256, 0, stream>>>(
        fmap[0], fmap[1], fmap[2], fmap[3], fmap[4], wT2, conv_b,
        (float*)hraw);
    heads_fused_kernel<float><<<dim3(211, 2), 256, 0, stream>>>(
        (float*)hraw, log_w, log_b, reg_w, reg_b, logits, regs);
  }
  topk_nms_kernel<<<10, 1024, 0, stream>>>(
      logits, regs, priors[0], priors[1], priors[2], priors[3], priors[4],
      imsizes, g_box, g_u, g_cnt);
  select_kernel<<<2, 256, 0, stream>>>(g_box, g_u, g_cnt, out);
}

// Round 14
// 1004.306 us; speedup vs baseline: 1.2458x; 1.0301x over previous
//
#include <hip/hip_runtime.h>
#include <math.h>

// RPN forward: fused conv3x3+relu (f64 MFMA implicit GEMM, layout-probed,
// reg-weights + dbuf input LDS, 2 sub-chunks/barrier) -> fused 1x1 heads ->
// [topk+decode+sort+NMS+compact] (10 blocks) -> per-image merge select.
// Precision: f64 everywhere decision-relevant (absmax 0 through R13).
// R12/R13: MFMA-busy constant 497us (~17.3cyc/mfma = 92% of 78.6TF f64
// spec) -> 497us is the conv pipe floor; idle 223us = barrier-per-623cyc +
// load stalls. R14: 8-ci per barrier (32 barriers, 1246cyc MFMA runs),
// 18 weight regs prefetched 1 iter ahead; transpose_w rewritten LDS-tiled
// (old version read stride-9216B per lane -> ~64 lines/wave, est ~100us).

#define N_IMG 2
#define C_CH  256
#define D_PER 2147
#define K_TOT 4294
#define CONV_BLOCKS 1912
#define CPX 239              // CONV_BLOCKS / 8 XCDs (exact)

typedef double v4d __attribute__((ext_vector_type(4)));

__constant__ int c_Ml[5]     = {30000, 7500, 1875, 507, 147};
__constant__ int c_kl[5]     = {500, 500, 500, 500, 147};
__constant__ int c_logoff[5] = {0, 60000, 75000, 78750, 79764};   // 6*cumE
__constant__ int c_regoff[5] = {0, 240000, 300000, 315000, 319056}; // 24*cumE
__constant__ int c_fs[5]     = {100, 50, 25, 13, 7};
__constant__ int c_npt[5]    = {13, 7, 4, 2, 1};
__constant__ int c_E[5]      = {10000, 2500, 625, 169, 49};
__constant__ int c_cumbl[6]  = {0, 1352, 1744, 1872, 1904, 1912};
__constant__ int c_hcum[6]   = {0, 157, 197, 207, 210, 211};
__constant__ size_t c_hoff[5] = {0, 5120000, 6400000, 6720000, 6806528};

// ------- weight repack+convert, LDS-tiled (coalesced both sides) ---------
// wT2 slab (cobi*64+ch4) = 2304 f64 = [tap9][ci4][co64].
__global__ __launch_bounds__(256) void transpose_w_kernel(
    const float* __restrict__ w, double* __restrict__ wT2) {
  __shared__ double s_t[2304];
  int slab = blockIdx.x;              // 0..255
  int cobi = slab >> 6, ch4 = slab & 63;
  int t = threadIdx.x;
  int co_l = t >> 2, ci = t & 3;
  const float* src =
      w + (size_t)(cobi * 64 + co_l) * 2304 + (ch4 * 4 + ci) * 9;
#pragma unroll
  for (int tap = 0; tap < 9; ++tap)
    s_t[tap * 256 + ci * 64 + co_l] = (double)src[tap];
  __syncthreads();
  double* dst = wT2 + (size_t)slab * 2304 + t * 9;
  const double* s = s_t + t * 9;
#pragma unroll
  for (int j = 0; j < 9; ++j) dst[j] = s[j];
}

// ------- fused conv3x3 (SAME) + bias + relu via f64 MFMA -----------------
// block: 256 thr = 4 waves; tile 64co x 64px (8x8). wave wv: co16 group.
// Per iteration (32 total): 8 ci staged in LDS (two 4-ci halves), 72 MFMA,
// weights 18 f64/lane in regs (prefetched), 1 barrier.
template <typename T>
__global__ __launch_bounds__(256) void conv_fused_kernel(
    const float* __restrict__ x0, const float* __restrict__ x1,
    const float* __restrict__ x2, const float* __restrict__ x3,
    const float* __restrict__ x4, const double* __restrict__ wT2,
    const float* __restrict__ bias, T* __restrict__ h) {
  __shared__ __align__(16) double s_in[2][960];  // dbuf [ci8][10x12]
  int tid = threadIdx.x;
  int bid = (blockIdx.x & 7) * CPX + (blockIdx.x >> 3);  // XCD swizzle
  int l = 0;
  while (bid >= c_cumbl[l + 1]) ++l;
  int r = bid - c_cumbl[l];
  int fs = c_fs[l], npt = c_npt[l];
  int tiles = npt * npt;
  int tile = r % tiles;
  int cn = r / tiles;
  int cobi = cn & 3, n = cn >> 2;
  int ptx = tile % npt, pty = tile / npt;
  int px0 = ptx * 8, py0 = pty * 8;
  int E = fs * fs;
  const float* xl;
  switch (l) {
    case 0: xl = x0; break;
    case 1: xl = x1; break;
    case 2: xl = x2; break;
    case 3: xl = x3; break;
    default: xl = x4; break;
  }
  const float* xn = xl + (size_t)n * C_CH * E;
  T* hl = h + c_hoff[l];

  int lane = tid & 63;
  int wv = tid >> 6;
  int lx = lane & 15;
  int lk = lane >> 4;

  // ---- layout calibration probes (verified R12) ----
  double ind0 = (lk == 0) ? 1.0 : 0.0;
  v4d pr1 = __builtin_amdgcn_mfma_f64_16x16x4f64((double)lx, ind0,
                                                 (v4d)0.0, 0, 0, 0);
  v4d pr2 = __builtin_amdgcn_mfma_f64_16x16x4f64(ind0, (double)lx,
                                                 (v4d)0.0, 0, 0, 0);
  int coL[4], pxL[4];
#pragma unroll
  for (int q = 0; q < 4; ++q) {
    coL[q] = (int)pr1[q];
    pxL[q] = (int)pr2[q];
  }

  // staging descriptors: 800 halo elems (8 ci x 100) over 256 thr, 4 slots
  int in_dst[4], in_src[4];
#pragma unroll
  for (int it = 0; it < 4; ++it) {
    int idx = tid + it * 256;
    in_dst[it] = -1;
    in_src[it] = -1;
    if (idx < 800) {
      int ci = idx / 100, rr2 = idx % 100;
      int hy = rr2 / 10, hx = rr2 % 10;
      int gy = py0 - 1 + hy, gx = px0 - 1 + hx;
      in_dst[it] = ci * 120 + hy * 12 + hx;
      if (gy >= 0 && gy < fs && gx >= 0 && gx < fs)
        in_src[it] = ci * E + gy * fs + gx;
    }
  }

  // per-lane B offsets within one 4-ci half
  int bOff[4];
#pragma unroll
  for (int p = 0; p < 4; ++p) {
    int pxidx = p * 16 + lx;
    bOff[p] = lk * 120 + (pxidx >> 3) * 12 + (pxidx & 7);
  }

  v4d acc[4];
#pragma unroll
  for (int p = 0; p < 4; ++p) acc[p] = (v4d)0.0;

  // per-lane weight pointer; iteration it consumes slabs 2it, 2it+1
  const double* wptr =
      wT2 + (size_t)cobi * 64 * 2304 + lk * 64 + wv * 16 + lx;

  double wcur[18], wnxt[18];
#pragma unroll
  for (int t = 0; t < 9; ++t) {
    wcur[t] = wptr[t * 256];
    wcur[9 + t] = wptr[2304 + t * 256];
  }
  {
    float v0[4];
#pragma unroll
    for (int it = 0; it < 4; ++it)
      v0[it] = (in_dst[it] >= 0 && in_src[it] >= 0) ? xn[in_src[it]] : 0.f;
#pragma unroll
    for (int it = 0; it < 4; ++it)
      if (in_dst[it] >= 0) s_in[0][in_dst[it]] = (double)v0[it];
  }
  __syncthreads();

  for (int it = 0; it < 32; ++it) {
    int buf = it & 1;
    bool more = (it + 1 < 32);
    float inx[4];
    if (more) {
      const float* xc1 = xn + (size_t)(it + 1) * 8 * E;
#pragma unroll
      for (int s = 0; s < 4; ++s)
        inx[s] = (in_dst[s] >= 0 && in_src[s] >= 0) ? xc1[in_src[s]] : 0.f;
      const double* wn = wptr + (size_t)(it + 1) * 4608;
#pragma unroll
      for (int t = 0; t < 9; ++t) {
        wnxt[t] = wn[t * 256];
        wnxt[9 + t] = wn[2304 + t * 256];
      }
    }
    const double* bbA = s_in[buf];
    const double* bbB = s_in[buf] + 480;
#pragma unroll
    for (int ky = 0; ky < 3; ++ky) {
#pragma unroll
      for (int kx = 0; kx < 3; ++kx) {
        int tap = ky * 3 + kx;
        int boff = ky * 12 + kx;
        double avA = wcur[tap];
#pragma unroll
        for (int p = 0; p < 4; ++p) {
          acc[p] = __builtin_amdgcn_mfma_f64_16x16x4f64(
              avA, bbA[bOff[p] + boff], acc[p], 0, 0, 0);
        }
      }
    }
#pragma unroll
    for (int ky = 0; ky < 3; ++ky) {
#pragma unroll
      for (int kx = 0; kx < 3; ++kx) {
        int tap = ky * 3 + kx;
        int boff = ky * 12 + kx;
        double avB = wcur[9 + tap];
#pragma unroll
        for (int p = 0; p < 4; ++p) {
          acc[p] = __builtin_amdgcn_mfma_f64_16x16x4f64(
              avB, bbB[bOff[p] + boff], acc[p], 0, 0, 0);
        }
      }
    }
    if (more) {
      double* db = s_in[buf ^ 1];
#pragma unroll
      for (int s = 0; s < 4; ++s)
        if (in_dst[s] >= 0) db[in_dst[s]] = (double)inx[s];
#pragma unroll
      for (int t = 0; t < 18; ++t) wcur[t] = wnxt[t];
    }
    __syncthreads();
  }

  // epilogue: probe-calibrated (lane,reg) -> (co_local, px_local)
#pragma unroll
  for (int p = 0; p < 4; ++p) {
#pragma unroll
    for (int rr2 = 0; rr2 < 4; ++rr2) {
      int pxidx = p * 16 + pxL[rr2];
      int gy = py0 + (pxidx >> 3), gx = px0 + (pxidx & 7);
      int co = cobi * 64 + wv * 16 + coL[rr2];
      if (gy < fs && gx < fs) {
        double v = acc[p][rr2] + (double)bias[co];
        hl[((size_t)n * C_CH + co) * E + gy * fs + gx] = (T)fmax(v, 0.0);
      }
    }
  }
}

// ------- fused 1x1 heads: 64 px x 4 c-groups per block, LDS reduce -------
template <typename T>
__global__ __launch_bounds__(256) void heads_fused_kernel(
    const T* __restrict__ h, const float* __restrict__ logw,
    const float* __restrict__ logb, const float* __restrict__ regw,
    const float* __restrict__ regb, double* __restrict__ logits,
    double* __restrict__ regs) {
  __shared__ float s_wh[256][16];
  __shared__ double s_red[4][15][64];
  int tid = threadIdx.x;
  int n = blockIdx.y;
  int cidx = blockIdx.x;
  int l = 0;
  while (cidx >= c_hcum[l + 1]) ++l;
  int chunk = cidx - c_hcum[l];
  int E = c_E[l];
  int px0 = chunk * 64;
  const T* hl = h + c_hoff[l];
  double* logits_l = logits + c_logoff[l];
  double* regs_l = regs + c_regoff[l];

  for (int idx = tid; idx < 4096; idx += 256) {
    int c = idx >> 4, j = idx & 15;
    float v = 0.f;
    if (j < 3) v = logw[j * 256 + c];
    else if (j < 15) v = regw[(j - 3) * 256 + c];
    s_wh[c][j] = v;
  }
  __syncthreads();

  int p = tid & 63, c4 = tid >> 6;
  int pix = px0 + p;
  bool act = pix < E;
  double acc[15];
#pragma unroll
  for (int j = 0; j < 15; j++) acc[j] = 0.0;
  if (act) {
    const T* hp = hl + ((size_t)n * C_CH + c4 * 64) * E + pix;
    for (int cc = 0; cc < 64; ++cc) {
      double hv = (double)hp[(size_t)cc * E];
      const float* wr = &s_wh[c4 * 64 + cc][0];
#pragma unroll
      for (int j = 0; j < 15; j++)
        acc[j] = fma((double)wr[j], hv, acc[j]);
    }
  }
#pragma unroll
  for (int j = 0; j < 15; j++) s_red[c4][j][p] = acc[j];
  __syncthreads();
  if (act) {
    int M = E * 3;
    for (int j = c4; j < 15; j += 4) {
      double v = s_red[0][j][p] + s_red[1][j][p] + s_red[2][j][p] +
                 s_red[3][j][p];
      if (j < 3) {
        logits_l[(size_t)n * M + pix * 3 + j] = v + (double)logb[j];
      } else {
        int rj = j - 3, a = rj >> 2, coord = rj & 3;
        regs_l[((size_t)n * M + pix * 3 + a) * 4 + coord] =
            v + (double)regb[rj];
      }
    }
  }
}

// ------- topk + decode + per-group sort + NMS + compact (10 blocks) ------
__device__ __forceinline__ unsigned long long d2key(double v) {
  unsigned long long ub = (unsigned long long)__double_as_longlong(v);
  return (ub >> 63) ? ~ub : (ub | 0x8000000000000000ull);
}

#define TK_CH 30
union TkShared {
  struct {
    int histw[16][256];
    int hist[256];
    int sgt[1024];
    int seq[1024];
  } a;
  struct {
    unsigned long long u[512];
    int idx[512];
    int keep[512];
    int ps[512];
    int m;
    double bx[512][4];
    unsigned long long mask[512][8];
  } b;
};

__global__ __launch_bounds__(1024) void topk_nms_kernel(
    const double* __restrict__ logits, const double* __restrict__ regs,
    const float* __restrict__ p0, const float* __restrict__ p1,
    const float* __restrict__ p2, const float* __restrict__ p3,
    const float* __restrict__ p4, const int* __restrict__ imsizes,
    double* __restrict__ g_box, unsigned long long* __restrict__ g_u,
    int* __restrict__ g_cnt) {
  __shared__ TkShared sh;
  __shared__ int s_sel[512];
  __shared__ unsigned long long s_prefix;
  __shared__ int s_r;
  int bid = blockIdx.x;
  int n = bid / 5, l = bid % 5;
  int M = c_Ml[l], k = c_kl[l];
  const double* lg = logits + c_logoff[l] + (size_t)n * M;
  int tid = threadIdx.x;
  if (tid == 0) { s_prefix = 0ull; s_r = k; }

  int chunk = (M + 1023) >> 10;
  int i0 = tid * chunk, i1 = min(M, i0 + chunk);
  int cnt = i1 - i0;
  if (cnt < 0) cnt = 0;
  unsigned long long kv[TK_CH];
#pragma unroll
  for (int q = 0; q < TK_CH; q++)
    if (q < cnt) kv[q] = d2key(lg[i0 + q]);
  int wid = tid >> 6;
  __syncthreads();

  for (int pass = 0; pass < 8; ++pass) {
    int shift = 56 - pass * 8;
    for (int i = tid; i < 4096; i += 1024) ((int*)sh.a.histw)[i] = 0;
    __syncthreads();
    unsigned long long pfx = s_prefix;
    int rr = s_r;
#pragma unroll
    for (int q = 0; q < TK_CH; q++) {
      if (q < cnt) {
        unsigned long long u = kv[q];
        if (pass == 0 || (u >> (shift + 8)) == pfx)
          atomicAdd(&sh.a.histw[wid][(int)((u >> shift) & 255ull)], 1);
      }
    }
    __syncthreads();
    if (tid < 256) {
      int s = 0;
#pragma unroll
      for (int w = 0; w < 16; w++) s += sh.a.histw[w][tid];
      sh.a.hist[tid] = s;
    }
    __syncthreads();
    if (tid == 0) {
      int s = 0, beta = 0;
      for (int b = 255; b >= 0; --b) {
        if (s + sh.a.hist[b] >= rr) { beta = b; break; }
        s += sh.a.hist[b];
      }
      s_prefix = (pfx << 8) | (unsigned long long)beta;
      s_r = rr - s;
    }
    __syncthreads();
  }
  unsigned long long T = s_prefix;
  int need = s_r;
  int cgt = 0, ceq = 0;
#pragma unroll
  for (int q = 0; q < TK_CH; q++) {
    if (q < cnt) {
      cgt += (kv[q] > T);
      ceq += (kv[q] == T);
    }
  }
  sh.a.sgt[tid] = cgt;
  sh.a.seq[tid] = ceq;
  __syncthreads();
  for (int o = 1; o < 1024; o <<= 1) {
    int a = (tid >= o) ? sh.a.sgt[tid - o] : 0;
    int b2 = (tid >= o) ? sh.a.seq[tid - o] : 0;
    __syncthreads();
    sh.a.sgt[tid] += a;
    sh.a.seq[tid] += b2;
    __syncthreads();
  }
  int gt_total = sh.a.sgt[1023];
  int pg = sh.a.sgt[tid] - cgt, pe = sh.a.seq[tid] - ceq;
#pragma unroll
  for (int q = 0; q < TK_CH; q++) {
    if (q < cnt) {
      unsigned long long u = kv[q];
      if (u > T) {
        s_sel[pg++] = i0 + q;
      } else if (u == T) {
        if (pe < need) s_sel[gt_total + pe] = i0 + q;
        pe++;
      }
    }
  }
  __syncthreads();

  const float* pp;
  switch (l) {
    case 0: pp = p0; break;
    case 1: pp = p1; break;
    case 2: pp = p2; break;
    case 3: pp = p3; break;
    default: pp = p4; break;
  }
  const double* regs_l = regs + c_regoff[l];
  double imh = (double)imsizes[n * 2 + 0], imw = (double)imsizes[n * 2 + 1];
  const double BCLIP = 4.1351665567423560;
  if (tid < 512) {
    unsigned long long key = 0ull;
    sh.b.idx[tid] = tid;
    sh.b.keep[tid] = 0;
    if (tid < k) {
      int aidx = s_sel[tid];
      double lv = lg[aidx];
      double obj = 1.0 / (1.0 + exp(-lv));
      const double* rp = regs_l + ((size_t)n * M + aidx) * 4;
      const float* pr = pp + (size_t)aidx * 4;
      double px1 = pr[0], py1 = pr[1], px2 = pr[2], py2 = pr[3];
      double pw = px2 - px1, ph = py2 - py1;
      double pcx = px1 + 0.5 * pw, pcy = py1 + 0.5 * ph;
      double dx = rp[0], dy = rp[1];
      double dw = fmin(rp[2], BCLIP), dh = fmin(rp[3], BCLIP);
      double cx = dx * pw + pcx, cy = dy * ph + pcy;
      double w = exp(dw) * pw, hh = exp(dh) * ph;
      double x1 = cx - 0.5 * w, y1 = cy - 0.5 * hh;
      double x2 = cx + 0.5 * w, y2 = cy + 0.5 * hh;
      x1 = fmin(fmax(x1, 0.0), imw);
      x2 = fmin(fmax(x2, 0.0), imw);
      y1 = fmin(fmax(y1, 0.0), imh);
      y2 = fmin(fmax(y2, 0.0), imh);
      bool valid = (obj >= 0.5) && ((x2 - x1) >= 1.0) && ((y2 - y1) >= 1.0);
      sh.b.bx[tid][0] = x1;
      sh.b.bx[tid][1] = y1;
      sh.b.bx[tid][2] = x2;
      sh.b.bx[tid][3] = y2;
      if (valid) key = d2key(obj);
    }
    sh.b.u[tid] = key;
  }
  if (tid == 0) sh.b.m = 0;
  __syncthreads();

  for (int kk = 2; kk <= 512; kk <<= 1) {
    for (int j = kk >> 1; j > 0; j >>= 1) {
      if (tid < 512) {
        int i = tid, ixj = i ^ j;
        if (ixj > i) {
          unsigned long long ua = sh.b.u[i], ub = sh.b.u[ixj];
          int ia = sh.b.idx[i], ib = sh.b.idx[ixj];
          bool up = ((i & kk) == 0);
          bool aAfterB = (ua < ub) || (ua == ub && ia > ib);
          bool sw = up ? aAfterB : !aAfterB && (ua != ub || ia != ib);
          if (sw) {
            sh.b.u[i] = ub; sh.b.u[ixj] = ua;
            sh.b.idx[i] = ib; sh.b.idx[ixj] = ia;
          }
        }
      }
      __syncthreads();
    }
  }
  if (tid < 512) {
    if (sh.b.u[tid] != 0ull && (tid == 511 || sh.b.u[tid + 1] == 0ull))
      sh.b.m = tid + 1;
  }
  __syncthreads();
  int m = sh.b.m;

  if (tid < 512 && tid < m) {
    int i = tid;
    const double* A = sh.b.bx[sh.b.idx[i]];
    double ax1 = A[0], ay1 = A[1], ax2 = A[2], ay2 = A[3];
    double areaA = (ax2 - ax1) * (ay2 - ay1);
    unsigned long long row[8] = {0, 0, 0, 0, 0, 0, 0, 0};
    for (int j = i + 1; j < m; ++j) {
      const double* B = sh.b.bx[sh.b.idx[j]];
      double bx1 = B[0], by1 = B[1], bx2 = B[2], by2 = B[3];
      double areaB = (bx2 - bx1) * (by2 - by1);
      double lx = fmax(ax1, bx1), ly = fmax(ay1, by1);
      double rx = fmin(ax2, bx2), ry = fmin(ay2, by2);
      double iw = fmax(rx - lx, 0.0), ih = fmax(ry - ly, 0.0);
      double inter = iw * ih;
      double iou = inter / (areaA + areaB - inter + 1e-9);
      if (iou > 0.7) row[j >> 6] |= (1ull << (j & 63));
    }
#pragma unroll
    for (int w2 = 0; w2 < 8; ++w2) sh.b.mask[i][w2] = row[w2];
  }
  __syncthreads();

  if (tid == 0) {
    unsigned long long remv[8] = {0, 0, 0, 0, 0, 0, 0, 0};
    for (int i = 0; i < m; ++i) {
      if (!((remv[i >> 6] >> (i & 63)) & 1ull)) {
        sh.b.keep[i] = 1;
#pragma unroll
        for (int w2 = 0; w2 < 8; ++w2) remv[w2] |= sh.b.mask[i][w2];
      }
    }
  }
  __syncthreads();

  if (tid < 512) sh.b.ps[tid] = sh.b.keep[tid];
  __syncthreads();
  for (int o = 1; o < 512; o <<= 1) {
    int v = 0;
    if (tid < 512 && tid >= o) v = sh.b.ps[tid - o];
    __syncthreads();
    if (tid < 512) sh.b.ps[tid] += v;
    __syncthreads();
  }
  if (tid < 512 && sh.b.keep[tid]) {
    int pos = sh.b.ps[tid] - 1;
    const double* B = sh.b.bx[sh.b.idx[tid]];
    size_t gbase = (size_t)bid * 512 + pos;
#pragma unroll
    for (int q = 0; q < 4; q++) g_box[gbase * 4 + q] = B[q];
    g_u[gbase] = sh.b.u[tid];
  }
  if (tid == 0) g_cnt[bid] = (m > 0) ? sh.b.ps[511] : 0;
}

// ------- per-image select: 5-way merge of sorted kept lists, top 100 -----
__global__ __launch_bounds__(256) void select_kernel(
    const double* __restrict__ g_box, const unsigned long long* __restrict__ g_u,
    const int* __restrict__ g_cnt, float* __restrict__ out) {
  __shared__ unsigned long long s_u[5][512];
  __shared__ int s_pick[100];
  __shared__ int s_total;
  int n = blockIdx.x;
  int tid = threadIdx.x;
  int cnts[5];
#pragma unroll
  for (int l = 0; l < 5; l++) cnts[l] = g_cnt[n * 5 + l];
  for (int idx = tid; idx < 5 * 512; idx += 256) {
    int l = idx >> 9, r = idx & 511;
    s_u[l][r] = (r < cnts[l]) ? g_u[(size_t)(n * 5 + l) * 512 + r] : 0ull;
  }
  __syncthreads();
  if (tid == 0) {
    int hd[5] = {0, 0, 0, 0, 0};
    int t = 0;
    while (t < 100) {
      int bl = -1;
      unsigned long long bu = 0ull;
      for (int l = 0; l < 5; l++) {
        if (hd[l] < cnts[l] && s_u[l][hd[l]] > bu) {
          bu = s_u[l][hd[l]];
          bl = l;
        }
      }
      if (bl < 0) break;
      s_pick[t++] = bl * 512 + hd[bl];
      hd[bl]++;
    }
    s_total = t;
  }
  __syncthreads();
  int total = s_total;
  for (int t = tid; t < 100; t += 256) {
    if (t < total) {
      int pk = s_pick[t];
      int l = pk >> 9, r = pk & 511;
      size_t gbase = (size_t)(n * 5 + l) * 512 + r;
#pragma unroll
      for (int q = 0; q < 4; q++)
        out[(n * 100 + t) * 4 + q] = (float)g_box[gbase * 4 + q];
      out[800 + n * 100 + t] = (float)n;
    } else {
#pragma unroll
      for (int q = 0; q < 4; q++) out[(n * 100 + t) * 4 + q] = 0.0f;
      out[800 + n * 100 + t] = -1.0f;
    }
  }
}

extern "C" void kernel_launch(void* const* d_in, const int* in_sizes, int n_in,
                              void* d_out, int out_size, void* d_ws,
                              size_t ws_size, hipStream_t stream) {
  (void)in_sizes; (void)n_in; (void)out_size;
  const float* fmap[5];
  const float* priors[5];
  for (int l = 0; l < 5; l++) {
    fmap[l] = (const float*)d_in[2 * l];        // interleaved input order!
    priors[l] = (const float*)d_in[2 * l + 1];
  }
  const float* conv_w = (const float*)d_in[10];
  const float* conv_b = (const float*)d_in[11];
  const float* log_w = (const float*)d_in[12];
  const float* log_b = (const float*)d_in[13];
  const float* reg_w = (const float*)d_in[14];
  const float* reg_b = (const float*)d_in[15];
  const int* imsizes = (const int*)d_in[16];
  float* out = (float*)d_out;

  bool f64h = ws_size >= (size_t)66000000;

  char* base = (char*)d_ws;
  size_t off = 0;
  auto alloc = [&](size_t bytes) -> void* {
    off = (off + 255) & ~(size_t)255;
    void* p = base + off;
    off += bytes;
    return p;
  };
  double* wT2 = (double*)alloc(589824ull * 8);
  void* hraw = alloc(6831616ull * (f64h ? 8 : 4));
  double* logits = (double*)alloc(80058ull * 8);
  double* regs = (double*)alloc(320232ull * 8);
  double* g_box = (double*)alloc(10ull * 512 * 4 * 8);
  unsigned long long* g_u = (unsigned long long*)alloc(10ull * 512 * 8);
  int* g_cnt = (int*)alloc(10 * 4);

  transpose_w_kernel<<<256, 256, 0, stream>>>(conv_w, wT2);

  if (f64h) {
    conv_fused_kernel<double><<<CONV_BLOCKS, 256, 0, stream>>>(
        fmap[0], fmap[1], fmap[2], fmap[3], fmap[4], wT2, conv_b,
        (double*)hraw);
    heads_fused_kernel<double><<<dim3(211, 2), 256, 0, stream>>>(
        (double*)hraw, log_w, log_b, reg_w, reg_b, logits, regs);
  } else {
    conv_fused_kernel<float><<<CONV_BLOCKS, 256, 0, stream>>>(
        fmap[0], fmap[1], fmap[2], fmap[3], fmap[4], wT2, conv_b,
        (float*)hraw);
    heads_fused_kernel<float><<<dim3(211, 2), 256, 0, stream>>>(
        (float*)hraw, log_w, log_b, reg_w, reg_b, logits, regs);
  }
  topk_nms_kernel<<<10, 1024, 0, stream>>>(
      logits, regs, priors[0], priors[1], priors[2], priors[3], priors[4],
      imsizes, g_box, g_u, g_cnt);
  select_kernel<<<2, 256, 0, stream>>>(g_box, g_u, g_cnt, out);
}

// Round 15
// 1002.328 us; speedup vs baseline: 1.2482x; 1.0020x over previous
//
#include <hip/hip_runtime.h>
#include <math.h>

// RPN forward: fused conv3x3+relu (f64 MFMA implicit GEMM, layout-probed,
// RAW-weight register loads, dbuf input LDS, 8ci/barrier) -> fused 1x1
// heads -> [topk+decode+sort+NMS+compact] (10 blocks) -> merge select.
// 4 dispatches. Precision: f64 everywhere decision-relevant (absmax 0).
// R12-R14: MFMA-busy pinned at ~499us (17.3cyc/mfma = 92% of f64 peak) =
// conv pipe floor. R14 tail stayed 316us despite transpose rewrite ->
// R15 deletes the transpose dispatch: each lane's A-fragment is 9
// CONTIGUOUS floats in raw conv_w ([co][ci][tap]) -> direct per-lane
// loads + in-register f32->f64 cvt (VALU 13% busy, free). Same MFMA
// order -> bit-identical output.

#define N_IMG 2
#define C_CH  256
#define D_PER 2147
#define K_TOT 4294
#define CONV_BLOCKS 1912
#define CPX 239              // CONV_BLOCKS / 8 XCDs (exact)

typedef double v4d __attribute__((ext_vector_type(4)));

__constant__ int c_Ml[5]     = {30000, 7500, 1875, 507, 147};
__constant__ int c_kl[5]     = {500, 500, 500, 500, 147};
__constant__ int c_logoff[5] = {0, 60000, 75000, 78750, 79764};   // 6*cumE
__constant__ int c_regoff[5] = {0, 240000, 300000, 315000, 319056}; // 24*cumE
__constant__ int c_fs[5]     = {100, 50, 25, 13, 7};
__constant__ int c_npt[5]    = {13, 7, 4, 2, 1};
__constant__ int c_E[5]      = {10000, 2500, 625, 169, 49};
__constant__ int c_cumbl[6]  = {0, 1352, 1744, 1872, 1904, 1912};
__constant__ int c_hcum[6]   = {0, 157, 197, 207, 210, 211};
__constant__ size_t c_hoff[5] = {0, 5120000, 6400000, 6720000, 6806528};

// ------- fused conv3x3 (SAME) + bias + relu via f64 MFMA -----------------
// block: 256 thr = 4 waves; tile 64co x 64px (8x8). wave wv: co16 group.
// Per iteration (32): 8 ci staged in LDS (two 4-ci halves), 72 MFMA,
// raw f32 weights 18/lane in regs (prefetched 1 iter ahead), 1 barrier.
template <typename T>
__global__ __launch_bounds__(256) void conv_fused_kernel(
    const float* __restrict__ x0, const float* __restrict__ x1,
    const float* __restrict__ x2, const float* __restrict__ x3,
    const float* __restrict__ x4, const float* __restrict__ wraw,
    const float* __restrict__ bias, T* __restrict__ h) {
  __shared__ __align__(16) double s_in[2][960];  // dbuf [ci8][10x12]
  int tid = threadIdx.x;
  int bid = (blockIdx.x & 7) * CPX + (blockIdx.x >> 3);  // XCD swizzle
  int l = 0;
  while (bid >= c_cumbl[l + 1]) ++l;
  int r = bid - c_cumbl[l];
  int fs = c_fs[l], npt = c_npt[l];
  int tiles = npt * npt;
  int tile = r % tiles;
  int cn = r / tiles;
  int cobi = cn & 3, n = cn >> 2;
  int ptx = tile % npt, pty = tile / npt;
  int px0 = ptx * 8, py0 = pty * 8;
  int E = fs * fs;
  const float* xl;
  switch (l) {
    case 0: xl = x0; break;
    case 1: xl = x1; break;
    case 2: xl = x2; break;
    case 3: xl = x3; break;
    default: xl = x4; break;
  }
  const float* xn = xl + (size_t)n * C_CH * E;
  T* hl = h + c_hoff[l];

  int lane = tid & 63;
  int wv = tid >> 6;
  int lx = lane & 15;
  int lk = lane >> 4;

  // ---- layout calibration probes (verified R12) ----
  double ind0 = (lk == 0) ? 1.0 : 0.0;
  v4d pr1 = __builtin_amdgcn_mfma_f64_16x16x4f64((double)lx, ind0,
                                                 (v4d)0.0, 0, 0, 0);
  v4d pr2 = __builtin_amdgcn_mfma_f64_16x16x4f64(ind0, (double)lx,
                                                 (v4d)0.0, 0, 0, 0);
  int coL[4], pxL[4];
#pragma unroll
  for (int q = 0; q < 4; ++q) {
    coL[q] = (int)pr1[q];
    pxL[q] = (int)pr2[q];
  }

  // staging descriptors: 800 halo elems (8 ci x 100) over 256 thr, 4 slots
  int in_dst[4], in_src[4];
#pragma unroll
  for (int it = 0; it < 4; ++it) {
    int idx = tid + it * 256;
    in_dst[it] = -1;
    in_src[it] = -1;
    if (idx < 800) {
      int ci = idx / 100, rr2 = idx % 100;
      int hy = rr2 / 10, hx = rr2 % 10;
      int gy = py0 - 1 + hy, gx = px0 - 1 + hx;
      in_dst[it] = ci * 120 + hy * 12 + hx;
      if (gy >= 0 && gy < fs && gx >= 0 && gx < fs)
        in_src[it] = ci * E + gy * fs + gx;
    }
  }

  // per-lane B offsets within one 4-ci half
  int bOff[4];
#pragma unroll
  for (int p = 0; p < 4; ++p) {
    int pxidx = p * 16 + lx;
    bOff[p] = lk * 120 + (pxidx >> 3) * 12 + (pxidx & 7);
  }

  v4d acc[4];
#pragma unroll
  for (int p = 0; p < 4; ++p) acc[p] = (v4d)0.0;

  // raw weight base for this lane's co; iteration it: ciA=it*8+lk,
  // ciB=it*8+4+lk; taps contiguous. 9 floats each half.
  const float* wp0 =
      wraw + (size_t)(cobi * 64 + wv * 16 + lx) * 2304;

  float wcur[18], wnxt[18];
  {
    const float* a = wp0 + lk * 9;
    const float* b = wp0 + (4 + lk) * 9;
#pragma unroll
    for (int t = 0; t < 9; ++t) {
      wcur[t] = a[t];
      wcur[9 + t] = b[t];
    }
  }
  {
    float v0[4];
#pragma unroll
    for (int it = 0; it < 4; ++it)
      v0[it] = (in_dst[it] >= 0 && in_src[it] >= 0) ? xn[in_src[it]] : 0.f;
#pragma unroll
    for (int it = 0; it < 4; ++it)
      if (in_dst[it] >= 0) s_in[0][in_dst[it]] = (double)v0[it];
  }
  __syncthreads();

  for (int it = 0; it < 32; ++it) {
    int buf = it & 1;
    bool more = (it + 1 < 32);
    float inx[4];
    if (more) {
      const float* xc1 = xn + (size_t)(it + 1) * 8 * E;
#pragma unroll
      for (int s = 0; s < 4; ++s)
        inx[s] = (in_dst[s] >= 0 && in_src[s] >= 0) ? xc1[in_src[s]] : 0.f;
      const float* a = wp0 + ((it + 1) * 8 + lk) * 9;
      const float* b = wp0 + ((it + 1) * 8 + 4 + lk) * 9;
#pragma unroll
      for (int t = 0; t < 9; ++t) {
        wnxt[t] = a[t];
        wnxt[9 + t] = b[t];
      }
    }
    const double* bbA = s_in[buf];
    const double* bbB = s_in[buf] + 480;
#pragma unroll
    for (int ky = 0; ky < 3; ++ky) {
#pragma unroll
      for (int kx = 0; kx < 3; ++kx) {
        int tap = ky * 3 + kx;
        int boff = ky * 12 + kx;
        double avA = (double)wcur[tap];
#pragma unroll
        for (int p = 0; p < 4; ++p) {
          acc[p] = __builtin_amdgcn_mfma_f64_16x16x4f64(
              avA, bbA[bOff[p] + boff], acc[p], 0, 0, 0);
        }
      }
    }
#pragma unroll
    for (int ky = 0; ky < 3; ++ky) {
#pragma unroll
      for (int kx = 0; kx < 3; ++kx) {
        int tap = ky * 3 + kx;
        int boff = ky * 12 + kx;
        double avB = (double)wcur[9 + tap];
#pragma unroll
        for (int p = 0; p < 4; ++p) {
          acc[p] = __builtin_amdgcn_mfma_f64_16x16x4f64(
              avB, bbB[bOff[p] + boff], acc[p], 0, 0, 0);
        }
      }
    }
    if (more) {
      double* db = s_in[buf ^ 1];
#pragma unroll
      for (int s = 0; s < 4; ++s)
        if (in_dst[s] >= 0) db[in_dst[s]] = (double)inx[s];
#pragma unroll
      for (int t = 0; t < 18; ++t) wcur[t] = wnxt[t];
    }
    __syncthreads();
  }

  // epilogue: probe-calibrated (lane,reg) -> (co_local, px_local)
#pragma unroll
  for (int p = 0; p < 4; ++p) {
#pragma unroll
    for (int rr2 = 0; rr2 < 4; ++rr2) {
      int pxidx = p * 16 + pxL[rr2];
      int gy = py0 + (pxidx >> 3), gx = px0 + (pxidx & 7);
      int co = cobi * 64 + wv * 16 + coL[rr2];
      if (gy < fs && gx < fs) {
        double v = acc[p][rr2] + (double)bias[co];
        hl[((size_t)n * C_CH + co) * E + gy * fs + gx] = (T)fmax(v, 0.0);
      }
    }
  }
}

// ------- fused 1x1 heads: 64 px x 4 c-groups per block, LDS reduce -------
template <typename T>
__global__ __launch_bounds__(256) void heads_fused_kernel(
    const T* __restrict__ h, const float* __restrict__ logw,
    const float* __restrict__ logb, const float* __restrict__ regw,
    const float* __restrict__ regb, double* __restrict__ logits,
    double* __restrict__ regs) {
  __shared__ float s_wh[256][16];
  __shared__ double s_red[4][15][64];
  int tid = threadIdx.x;
  int n = blockIdx.y;
  int cidx = blockIdx.x;
  int l = 0;
  while (cidx >= c_hcum[l + 1]) ++l;
  int chunk = cidx - c_hcum[l];
  int E = c_E[l];
  int px0 = chunk * 64;
  const T* hl = h + c_hoff[l];
  double* logits_l = logits + c_logoff[l];
  double* regs_l = regs + c_regoff[l];

  for (int idx = tid; idx < 4096; idx += 256) {
    int c = idx >> 4, j = idx & 15;
    float v = 0.f;
    if (j < 3) v = logw[j * 256 + c];
    else if (j < 15) v = regw[(j - 3) * 256 + c];
    s_wh[c][j] = v;
  }
  __syncthreads();

  int p = tid & 63, c4 = tid >> 6;
  int pix = px0 + p;
  bool act = pix < E;
  double acc[15];
#pragma unroll
  for (int j = 0; j < 15; j++) acc[j] = 0.0;
  if (act) {
    const T* hp = hl + ((size_t)n * C_CH + c4 * 64) * E + pix;
    for (int cc = 0; cc < 64; ++cc) {
      double hv = (double)hp[(size_t)cc * E];
      const float* wr = &s_wh[c4 * 64 + cc][0];
#pragma unroll
      for (int j = 0; j < 15; j++)
        acc[j] = fma((double)wr[j], hv, acc[j]);
    }
  }
#pragma unroll
  for (int j = 0; j < 15; j++) s_red[c4][j][p] = acc[j];
  __syncthreads();
  if (act) {
    int M = E * 3;
    for (int j = c4; j < 15; j += 4) {
      double v = s_red[0][j][p] + s_red[1][j][p] + s_red[2][j][p] +
                 s_red[3][j][p];
      if (j < 3) {
        logits_l[(size_t)n * M + pix * 3 + j] = v + (double)logb[j];
      } else {
        int rj = j - 3, a = rj >> 2, coord = rj & 3;
        regs_l[((size_t)n * M + pix * 3 + a) * 4 + coord] =
            v + (double)regb[rj];
      }
    }
  }
}

// ------- topk + decode + per-group sort + NMS + compact (10 blocks) ------
__device__ __forceinline__ unsigned long long d2key(double v) {
  unsigned long long ub = (unsigned long long)__double_as_longlong(v);
  return (ub >> 63) ? ~ub : (ub | 0x8000000000000000ull);
}

#define TK_CH 30
union TkShared {
  struct {
    int histw[16][256];
    int hist[256];
    int sgt[1024];
    int seq[1024];
  } a;
  struct {
    unsigned long long u[512];
    int idx[512];
    int keep[512];
    int ps[512];
    int m;
    double bx[512][4];
    unsigned long long mask[512][8];
  } b;
};

__global__ __launch_bounds__(1024) void topk_nms_kernel(
    const double* __restrict__ logits, const double* __restrict__ regs,
    const float* __restrict__ p0, const float* __restrict__ p1,
    const float* __restrict__ p2, const float* __restrict__ p3,
    const float* __restrict__ p4, const int* __restrict__ imsizes,
    double* __restrict__ g_box, unsigned long long* __restrict__ g_u,
    int* __restrict__ g_cnt) {
  __shared__ TkShared sh;
  __shared__ int s_sel[512];
  __shared__ unsigned long long s_prefix;
  __shared__ int s_r;
  int bid = blockIdx.x;
  int n = bid / 5, l = bid % 5;
  int M = c_Ml[l], k = c_kl[l];
  const double* lg = logits + c_logoff[l] + (size_t)n * M;
  int tid = threadIdx.x;
  if (tid == 0) { s_prefix = 0ull; s_r = k; }

  int chunk = (M + 1023) >> 10;
  int i0 = tid * chunk, i1 = min(M, i0 + chunk);
  int cnt = i1 - i0;
  if (cnt < 0) cnt = 0;
  unsigned long long kv[TK_CH];
#pragma unroll
  for (int q = 0; q < TK_CH; q++)
    if (q < cnt) kv[q] = d2key(lg[i0 + q]);
  int wid = tid >> 6;
  __syncthreads();

  for (int pass = 0; pass < 8; ++pass) {
    int shift = 56 - pass * 8;
    for (int i = tid; i < 4096; i += 1024) ((int*)sh.a.histw)[i] = 0;
    __syncthreads();
    unsigned long long pfx = s_prefix;
    int rr = s_r;
#pragma unroll
    for (int q = 0; q < TK_CH; q++) {
      if (q < cnt) {
        unsigned long long u = kv[q];
        if (pass == 0 || (u >> (shift + 8)) == pfx)
          atomicAdd(&sh.a.histw[wid][(int)((u >> shift) & 255ull)], 1);
      }
    }
    __syncthreads();
    if (tid < 256) {
      int s = 0;
#pragma unroll
      for (int w = 0; w < 16; w++) s += sh.a.histw[w][tid];
      sh.a.hist[tid] = s;
    }
    __syncthreads();
    if (tid == 0) {
      int s = 0, beta = 0;
      for (int b = 255; b >= 0; --b) {
        if (s + sh.a.hist[b] >= rr) { beta = b; break; }
        s += sh.a.hist[b];
      }
      s_prefix = (pfx << 8) | (unsigned long long)beta;
      s_r = rr - s;
    }
    __syncthreads();
  }
  unsigned long long T = s_prefix;
  int need = s_r;
  int cgt = 0, ceq = 0;
#pragma unroll
  for (int q = 0; q < TK_CH; q++) {
    if (q < cnt) {
      cgt += (kv[q] > T);
      ceq += (kv[q] == T);
    }
  }
  sh.a.sgt[tid] = cgt;
  sh.a.seq[tid] = ceq;
  __syncthreads();
  for (int o = 1; o < 1024; o <<= 1) {
    int a = (tid >= o) ? sh.a.sgt[tid - o] : 0;
    int b2 = (tid >= o) ? sh.a.seq[tid - o] : 0;
    __syncthreads();
    sh.a.sgt[tid] += a;
    sh.a.seq[tid] += b2;
    __syncthreads();
  }
  int gt_total = sh.a.sgt[1023];
  int pg = sh.a.sgt[tid] - cgt, pe = sh.a.seq[tid] - ceq;
#pragma unroll
  for (int q = 0; q < TK_CH; q++) {
    if (q < cnt) {
      unsigned long long u = kv[q];
      if (u > T) {
        s_sel[pg++] = i0 + q;
      } else if (u == T) {
        if (pe < need) s_sel[gt_total + pe] = i0 + q;
        pe++;
      }
    }
  }
  __syncthreads();

  const float* pp;
  switch (l) {
    case 0: pp = p0; break;
    case 1: pp = p1; break;
    case 2: pp = p2; break;
    case 3: pp = p3; break;
    default: pp = p4; break;
  }
  const double* regs_l = regs + c_regoff[l];
  double imh = (double)imsizes[n * 2 + 0], imw = (double)imsizes[n * 2 + 1];
  const double BCLIP = 4.1351665567423560;
  if (tid < 512) {
    unsigned long long key = 0ull;
    sh.b.idx[tid] = tid;
    sh.b.keep[tid] = 0;
    if (tid < k) {
      int aidx = s_sel[tid];
      double lv = lg[aidx];
      double obj = 1.0 / (1.0 + exp(-lv));
      const double* rp = regs_l + ((size_t)n * M + aidx) * 4;
      const float* pr = pp + (size_t)aidx * 4;
      double px1 = pr[0], py1 = pr[1], px2 = pr[2], py2 = pr[3];
      double pw = px2 - px1, ph = py2 - py1;
      double pcx = px1 + 0.5 * pw, pcy = py1 + 0.5 * ph;
      double dx = rp[0], dy = rp[1];
      double dw = fmin(rp[2], BCLIP), dh = fmin(rp[3], BCLIP);
      double cx = dx * pw + pcx, cy = dy * ph + pcy;
      double w = exp(dw) * pw, hh = exp(dh) * ph;
      double x1 = cx - 0.5 * w, y1 = cy - 0.5 * hh;
      double x2 = cx + 0.5 * w, y2 = cy + 0.5 * hh;
      x1 = fmin(fmax(x1, 0.0), imw);
      x2 = fmin(fmax(x2, 0.0), imw);
      y1 = fmin(fmax(y1, 0.0), imh);
      y2 = fmin(fmax(y2, 0.0), imh);
      bool valid = (obj >= 0.5) && ((x2 - x1) >= 1.0) && ((y2 - y1) >= 1.0);
      sh.b.bx[tid][0] = x1;
      sh.b.bx[tid][1] = y1;
      sh.b.bx[tid][2] = x2;
      sh.b.bx[tid][3] = y2;
      if (valid) key = d2key(obj);
    }
    sh.b.u[tid] = key;
  }
  if (tid == 0) sh.b.m = 0;
  __syncthreads();

  for (int kk = 2; kk <= 512; kk <<= 1) {
    for (int j = kk >> 1; j > 0; j >>= 1) {
      if (tid < 512) {
        int i = tid, ixj = i ^ j;
        if (ixj > i) {
          unsigned long long ua = sh.b.u[i], ub = sh.b.u[ixj];
          int ia = sh.b.idx[i], ib = sh.b.idx[ixj];
          bool up = ((i & kk) == 0);
          bool aAfterB = (ua < ub) || (ua == ub && ia > ib);
          bool sw = up ? aAfterB : !aAfterB && (ua != ub || ia != ib);
          if (sw) {
            sh.b.u[i] = ub; sh.b.u[ixj] = ua;
            sh.b.idx[i] = ib; sh.b.idx[ixj] = ia;
          }
        }
      }
      __syncthreads();
    }
  }
  if (tid < 512) {
    if (sh.b.u[tid] != 0ull && (tid == 511 || sh.b.u[tid + 1] == 0ull))
      sh.b.m = tid + 1;
  }
  __syncthreads();
  int m = sh.b.m;

  if (tid < 512 && tid < m) {
    int i = tid;
    const double* A = sh.b.bx[sh.b.idx[i]];
    double ax1 = A[0], ay1 = A[1], ax2 = A[2], ay2 = A[3];
    double areaA = (ax2 - ax1) * (ay2 - ay1);
    unsigned long long row[8] = {0, 0, 0, 0, 0, 0, 0, 0};
    for (int j = i + 1; j < m; ++j) {
      const double* B = sh.b.bx[sh.b.idx[j]];
      double bx1 = B[0], by1 = B[1], bx2 = B[2], by2 = B[3];
      double areaB = (bx2 - bx1) * (by2 - by1);
      double lx = fmax(ax1, bx1), ly = fmax(ay1, by1);
      double rx = fmin(ax2, bx2), ry = fmin(ay2, by2);
      double iw = fmax(rx - lx, 0.0), ih = fmax(ry - ly, 0.0);
      double inter = iw * ih;
      double iou = inter / (areaA + areaB - inter + 1e-9);
      if (iou > 0.7) row[j >> 6] |= (1ull << (j & 63));
    }
#pragma unroll
    for (int w2 = 0; w2 < 8; ++w2) sh.b.mask[i][w2] = row[w2];
  }
  __syncthreads();

  if (tid == 0) {
    unsigned long long remv[8] = {0, 0, 0, 0, 0, 0, 0, 0};
    for (int i = 0; i < m; ++i) {
      if (!((remv[i >> 6] >> (i & 63)) & 1ull)) {
        sh.b.keep[i] = 1;
#pragma unroll
        for (int w2 = 0; w2 < 8; ++w2) remv[w2] |= sh.b.mask[i][w2];
      }
    }
  }
  __syncthreads();

  if (tid < 512) sh.b.ps[tid] = sh.b.keep[tid];
  __syncthreads();
  for (int o = 1; o < 512; o <<= 1) {
    int v = 0;
    if (tid < 512 && tid >= o) v = sh.b.ps[tid - o];
    __syncthreads();
    if (tid < 512) sh.b.ps[tid] += v;
    __syncthreads();
  }
  if (tid < 512 && sh.b.keep[tid]) {
    int pos = sh.b.ps[tid] - 1;
    const double* B = sh.b.bx[sh.b.idx[tid]];
    size_t gbase = (size_t)bid * 512 + pos;
#pragma unroll
    for (int q = 0; q < 4; q++) g_box[gbase * 4 + q] = B[q];
    g_u[gbase] = sh.b.u[tid];
  }
  if (tid == 0) g_cnt[bid] = (m > 0) ? sh.b.ps[511] : 0;
}

// ------- per-image select: 5-way merge of sorted kept lists, top 100 -----
__global__ __launch_bounds__(256) void select_kernel(
    const double* __restrict__ g_box, const unsigned long long* __restrict__ g_u,
    const int* __restrict__ g_cnt, float* __restrict__ out) {
  __shared__ unsigned long long s_u[5][512];
  __shared__ int s_pick[100];
  __shared__ int s_total;
  int n = blockIdx.x;
  int tid = threadIdx.x;
  int cnts[5];
#pragma unroll
  for (int l = 0; l < 5; l++) cnts[l] = g_cnt[n * 5 + l];
  for (int idx = tid; idx < 5 * 512; idx += 256) {
    int l = idx >> 9, r = idx & 511;
    s_u[l][r] = (r < cnts[l]) ? g_u[(size_t)(n * 5 + l) * 512 + r] : 0ull;
  }
  __syncthreads();
  if (tid == 0) {
    int hd[5] = {0, 0, 0, 0, 0};
    int t = 0;
    while (t < 100) {
      int bl = -1;
      unsigned long long bu = 0ull;
      for (int l = 0; l < 5; l++) {
        if (hd[l] < cnts[l] && s_u[l][hd[l]] > bu) {
          bu = s_u[l][hd[l]];
          bl = l;
        }
      }
      if (bl < 0) break;
      s_pick[t++] = bl * 512 + hd[bl];
      hd[bl]++;
    }
    s_total = t;
  }
  __syncthreads();
  int total = s_total;
  for (int t = tid; t < 100; t += 256) {
    if (t < total) {
      int pk = s_pick[t];
      int l = pk >> 9, r = pk & 511;
      size_t gbase = (size_t)(n * 5 + l) * 512 + r;
#pragma unroll
      for (int q = 0; q < 4; q++)
        out[(n * 100 + t) * 4 + q] = (float)g_box[gbase * 4 + q];
      out[800 + n * 100 + t] = (float)n;
    } else {
#pragma unroll
      for (int q = 0; q < 4; q++) out[(n * 100 + t) * 4 + q] = 0.0f;
      out[800 + n * 100 + t] = -1.0f;
    }
  }
}

extern "C" void kernel_launch(void* const* d_in, const int* in_sizes, int n_in,
                              void* d_out, int out_size, void* d_ws,
                              size_t ws_size, hipStream_t stream) {
  (void)in_sizes; (void)n_in; (void)out_size;
  const float* fmap[5];
  const float* priors[5];
  for (int l = 0; l < 5; l++) {
    fmap[l] = (const float*)d_in[2 * l];        // interleaved input order!
    priors[l] = (const float*)d_in[2 * l + 1];
  }
  const float* conv_w = (const float*)d_in[10];
  const float* conv_b = (const float*)d_in[11];
  const float* log_w = (const float*)d_in[12];
  const float* log_b = (const float*)d_in[13];
  const float* reg_w = (const float*)d_in[14];
  const float* reg_b = (const float*)d_in[15];
  const int* imsizes = (const int*)d_in[16];
  float* out = (float*)d_out;

  bool f64h = ws_size >= (size_t)60000000;

  char* base = (char*)d_ws;
  size_t off = 0;
  auto alloc = [&](size_t bytes) -> void* {
    off = (off + 255) & ~(size_t)255;
    void* p = base + off;
    off += bytes;
    return p;
  };
  void* hraw = alloc(6831616ull * (f64h ? 8 : 4));
  double* logits = (double*)alloc(80058ull * 8);
  double* regs = (double*)alloc(320232ull * 8);
  double* g_box = (double*)alloc(10ull * 512 * 4 * 8);
  unsigned long long* g_u = (unsigned long long*)alloc(10ull * 512 * 8);
  int* g_cnt = (int*)alloc(10 * 4);

  if (f64h) {
    conv_fused_kernel<double><<<CONV_BLOCKS, 256, 0, stream>>>(
        fmap[0], fmap[1], fmap[2], fmap[3], fmap[4], conv_w, conv_b,
        (double*)hraw);
    heads_fused_kernel<double><<<dim3(211, 2), 256, 0, stream>>>(
        (double*)hraw, log_w, log_b, reg_w, reg_b, logits, regs);
  } else {
    conv_fused_kernel<float><<<CONV_BLOCKS, 256, 0, stream>>>(
        fmap[0], fmap[1], fmap[2], fmap[3], fmap[4], conv_w, conv_b,
        (float*)hraw);
    heads_fused_kernel<float><<<dim3(211, 2), 256, 0, stream>>>(
        (float*)hraw, log_w, log_b, reg_w, reg_b, logits, regs);
  }
  topk_nms_kernel<<<10, 1024, 0, stream>>>(
      logits, regs, priors[0], priors[1], priors[2], priors[3], priors[4],
      imsizes, g_box, g_u, g_cnt);
  select_kernel<<<2, 256, 0, stream>>>(g_box, g_u, g_cnt, out);
}